// Round 15
// baseline (470.866 us; speedup 1.0000x reference)
//
#include <hip/hip_runtime.h>
#include <hip/hip_bf16.h>
#include <stdint.h>

typedef unsigned short u16;
typedef unsigned int u32;
typedef short bf16x8 __attribute__((ext_vector_type(8)));
typedef float f32x4 __attribute__((ext_vector_type(4)));

#define SCALE_F 0.088388347648318447f   // 1/sqrt(128)
#define LAMBDA_INIT_F 0.2f
// B=2, T=1024, DIM=4096, H=32, Hk=8, D=128, NREP=4

__device__ __forceinline__ u16 f2bf(float f) {
  union { float f; u32 u; } v; v.f = f;
  u32 r = v.u + 0x7fffu + ((v.u >> 16) & 1u);   // RNE
  return (u16)(r >> 16);
}
__device__ __forceinline__ float bf2f(u16 u) {
  union { u32 u; float f; } v; v.u = ((u32)u) << 16;
  return v.f;
}

typedef __attribute__((address_space(1))) void gvoid_t;
typedef __attribute__((address_space(3))) void lvoid_t;
__device__ __forceinline__ void gload16(const void* g, void* l) {
  __builtin_amdgcn_global_load_lds((gvoid_t*)g, (lvoid_t*)l, 16, 0, 0);
}

// ---------------- elementwise cast f32 -> bf16 (vectorized) ----------------
__global__ void cast_f32_bf16(const float4* __restrict__ in, uint2* __restrict__ out, int n4) {
  int i = blockIdx.x * 256 + threadIdx.x;
  if (i >= n4) return;
  float4 v = in[i];
  uint2 o;
  o.x = (u32)f2bf(v.x) | ((u32)f2bf(v.y) << 16);
  o.y = (u32)f2bf(v.z) | ((u32)f2bf(v.w) << 16);
  out[i] = o;
}

// ------ transpose+cast: w (K,N) f32 -> wt (N,K) bf16, u32-packed stores ------
__global__ void trans_cast(const float* __restrict__ in, u16* __restrict__ out, int K, int N) {
  __shared__ float tile[64][33];
  int kt = blockIdx.y * 64, nt = blockIdx.x * 32;
  int x = threadIdx.x, y = threadIdx.y;   // (32,8)
  #pragma unroll
  for (int j = 0; j < 8; ++j)
    tile[y + j * 8][x] = in[(size_t)(kt + y + j * 8) * N + nt + x];
  __syncthreads();
  #pragma unroll
  for (int j = 0; j < 4; ++j) {
    int n = y * 4 + j;
    u32 pk = (u32)f2bf(tile[2 * x][n]) | ((u32)f2bf(tile[2 * x + 1][n]) << 16);
    *(u32*)&out[(size_t)(nt + n) * K + kt + 2 * x] = pk;
  }
}

// ====== gemmW (r15): 128x128, BK=32, 2 waves (128x64 each), 3 blocks/CU ======
// r14 NaN bug fixed: with 128 threads each gload16 group covers 1024 u16
// (32 rows), so dest offsets are +1024/+2048/+3072 (r14 had the 256-thread
// values +2048/+4096/+6144 -> rows misplaced AND B group 3 wrote past its
// 4 KB buffer into the next ring slot). TN=88 == 0 mod 8 -> B panel
// XCD-pinned (r2/r6 low-FETCH property). 1408 blocks at 3/CU = 92% packing.
// Ring-3 / counted-vmcnt(8) / single-barrier schedule (r12-verified).
#define WSA(buf, t) { \
  gload16(Aq + (size_t)(t) * 32, (buf) + qdst); \
  gload16(Aq + (size_t)32 * K + (size_t)(t) * 32, (buf) + 1024 + qdst); \
  gload16(Aq + (size_t)64 * K + (size_t)(t) * 32, (buf) + 2048 + qdst); \
  gload16(Aq + (size_t)96 * K + (size_t)(t) * 32, (buf) + 3072 + qdst); }
#define WSB(buf, t) { \
  gload16(Bq + (size_t)(t) * 32, (buf) + qdst); \
  gload16(Bq + (size_t)32 * K + (size_t)(t) * 32, (buf) + 1024 + qdst); \
  gload16(Bq + (size_t)64 * K + (size_t)(t) * 32, (buf) + 2048 + qdst); \
  gload16(Bq + (size_t)96 * K + (size_t)(t) * 32, (buf) + 3072 + qdst); }
#define QMFMA16(O) { \
  acc[O+0][0] = __builtin_amdgcn_mfma_f32_16x16x32_bf16(a0, b0, acc[O+0][0], 0, 0, 0); \
  acc[O+0][1] = __builtin_amdgcn_mfma_f32_16x16x32_bf16(a0, b1, acc[O+0][1], 0, 0, 0); \
  acc[O+0][2] = __builtin_amdgcn_mfma_f32_16x16x32_bf16(a0, b2, acc[O+0][2], 0, 0, 0); \
  acc[O+0][3] = __builtin_amdgcn_mfma_f32_16x16x32_bf16(a0, b3, acc[O+0][3], 0, 0, 0); \
  acc[O+1][0] = __builtin_amdgcn_mfma_f32_16x16x32_bf16(a1, b0, acc[O+1][0], 0, 0, 0); \
  acc[O+1][1] = __builtin_amdgcn_mfma_f32_16x16x32_bf16(a1, b1, acc[O+1][1], 0, 0, 0); \
  acc[O+1][2] = __builtin_amdgcn_mfma_f32_16x16x32_bf16(a1, b2, acc[O+1][2], 0, 0, 0); \
  acc[O+1][3] = __builtin_amdgcn_mfma_f32_16x16x32_bf16(a1, b3, acc[O+1][3], 0, 0, 0); \
  acc[O+2][0] = __builtin_amdgcn_mfma_f32_16x16x32_bf16(a2, b0, acc[O+2][0], 0, 0, 0); \
  acc[O+2][1] = __builtin_amdgcn_mfma_f32_16x16x32_bf16(a2, b1, acc[O+2][1], 0, 0, 0); \
  acc[O+2][2] = __builtin_amdgcn_mfma_f32_16x16x32_bf16(a2, b2, acc[O+2][2], 0, 0, 0); \
  acc[O+2][3] = __builtin_amdgcn_mfma_f32_16x16x32_bf16(a2, b3, acc[O+2][3], 0, 0, 0); \
  acc[O+3][0] = __builtin_amdgcn_mfma_f32_16x16x32_bf16(a3, b0, acc[O+3][0], 0, 0, 0); \
  acc[O+3][1] = __builtin_amdgcn_mfma_f32_16x16x32_bf16(a3, b1, acc[O+3][1], 0, 0, 0); \
  acc[O+3][2] = __builtin_amdgcn_mfma_f32_16x16x32_bf16(a3, b2, acc[O+3][2], 0, 0, 0); \
  acc[O+3][3] = __builtin_amdgcn_mfma_f32_16x16x32_bf16(a3, b3, acc[O+3][3], 0, 0, 0); }

__global__ __launch_bounds__(128, 2) void gemmW(const u16* __restrict__ A,
                                                const u16* __restrict__ Bt,
                                                u16* __restrict__ vb,   // (B*T, 1024) V out
                                                u16* __restrict__ qrp,  // (B,64,T,128)
                                                u16* __restrict__ krp,  // (B,16,T,128)
                                                const float* __restrict__ cosp,
                                                const float* __restrict__ sinp,
                                                int K, int TN) {
  extern __shared__ u16 lds[];   // A bufs: 0/4096/8192, B bufs: 12288/16384/20480 (u16)
  const int tid = threadIdx.x;
  const int lane = tid & 63;
  const int wn = tid >> 6;                   // 2 waves: col halves
  const int ln = lane & 15, gr = lane >> 4;
  const int NT = K >> 5;

  const int bid = blockIdx.x;                // N-major; TN=88 -> XCD-pinned B
  const int bn = (bid % TN) * 128;
  const int bm = (bid / TN) * 128;

  const int sch = (tid & 3) ^ ((tid >> 3) & 3);
  const u16* Aq = A + (size_t)(bm + (tid >> 2)) * K + sch * 8;
  const u16* Bq = Bt + (size_t)(bn + (tid >> 2)) * K + sch * 8;
  const int qdst = tid * 8;

  const int cfo = (gr ^ ((ln >> 1) & 3)) * 8;
  const int ab = ln * 32 + cfo;              // + mf*512
  const int bb = wn * 2048 + ln * 32 + cfo;  // + nf*512

  f32x4 acc[8][4] = {};
  bf16x8 a0, a1, a2, a3, b0, b1, b2, b3;

  // prologue: A(0),B(0),A(1),B(1) = 16 loads; vmcnt(8) -> tile0 landed
  WSA(lds, 0);
  WSB(lds + 12288, 0);
  WSA(lds + 4096, 1);
  WSB(lds + 16384, 1);
  asm volatile("s_waitcnt vmcnt(8)" ::: "memory");
  __builtin_amdgcn_s_barrier();

  int tm3 = 0;
  for (int t = 0; t < NT; ++t) {
    const u16* Ac = lds + tm3 * 4096;
    const u16* Bc = lds + 12288 + tm3 * 4096;
    int tn3 = tm3 + 2; if (tn3 >= 3) tn3 -= 3;
    u16* An = lds + tn3 * 4096;
    u16* Bn = lds + 12288 + tn3 * 4096;

    // ---- phase 0: m-half 0, all b-frags (b reused in ph1) ----
    a0 = *(const bf16x8*)&Ac[ab];
    a1 = *(const bf16x8*)&Ac[ab + 512];
    a2 = *(const bf16x8*)&Ac[ab + 1024];
    a3 = *(const bf16x8*)&Ac[ab + 1536];
    b0 = *(const bf16x8*)&Bc[bb];
    b1 = *(const bf16x8*)&Bc[bb + 512];
    b2 = *(const bf16x8*)&Bc[bb + 1024];
    b3 = *(const bf16x8*)&Bc[bb + 1536];
    if (t + 2 < NT) WSA(An, t + 2);
    __builtin_amdgcn_s_setprio(1);
    QMFMA16(0);
    __builtin_amdgcn_s_setprio(0);

    // ---- phase 1: m-half 1 ----
    a0 = *(const bf16x8*)&Ac[ab + 2048];
    a1 = *(const bf16x8*)&Ac[ab + 2560];
    a2 = *(const bf16x8*)&Ac[ab + 3072];
    a3 = *(const bf16x8*)&Ac[ab + 3584];
    if (t + 2 < NT) {
      WSB(Bn, t + 2);
      asm volatile("s_waitcnt vmcnt(8)" ::: "memory");
    } else {
      asm volatile("s_waitcnt vmcnt(0)" ::: "memory");
    }
    __builtin_amdgcn_s_setprio(1);
    QMFMA16(4);
    __builtin_amdgcn_s_setprio(0);
    __builtin_amdgcn_s_barrier();          // single barrier per K-tile

    tm3 = (tm3 + 1 == 3) ? 0 : tm3 + 1;
  }

  // ---------------- fused epilogue ----------------
  if (bn < 10240) {
    // Q/K panel (exactly 1 head): acc -> LDS bf16 (stride 136), rope, write
    #pragma unroll
    for (int mf = 0; mf < 8; ++mf)
      #pragma unroll
      for (int j = 0; j < 4; ++j) {
        int rl = mf * 16 + gr * 4 + j;
        #pragma unroll
        for (int nf = 0; nf < 4; ++nf)
          lds[rl * 136 + wn * 64 + nf * 16 + ln] = f2bf(acc[mf][nf][j]);
      }
    __syncthreads();
    const int bb_ = bm >> 10;              // batch (rows never cross b)
    const int gt0 = bm & 1023;             // sequence offset of row 0
    const bool isQ = (bn < 8192);
    const int hh = isQ ? (bn >> 7) : ((bn - 8192) >> 7);
    const int NHh = isQ ? 64 : 16;
    u16* outp = isQ ? qrp : krp;
    const int tr = tid >> 5;               // 4 row-groups
    const int d2 = (tid & 31) * 2;         // even d, u32 granularity
    #pragma unroll
    for (int r4 = 0; r4 < 32; ++r4) {
      int t = r4 * 4 + tr;
      int gt = gt0 + t;
      float2 cc = *(const float2*)&cosp[gt * 64 + d2];
      float2 sv = *(const float2*)&sinp[gt * 64 + d2];
      u32 p1 = *(const u32*)&lds[t * 136 + d2];
      u32 p2 = *(const u32*)&lds[t * 136 + 64 + d2];
      float x1a = bf2f((u16)p1), x1b = bf2f((u16)(p1 >> 16));
      float x2a = bf2f((u16)p2), x2b = bf2f((u16)(p2 >> 16));
      u32 o1 = (u32)f2bf(x1a * cc.x - x2a * sv.x) | ((u32)f2bf(x1b * cc.y - x2b * sv.y) << 16);
      u32 o2 = (u32)f2bf(x2a * cc.x + x1a * sv.x) | ((u32)f2bf(x2b * cc.y + x1b * sv.y) << 16);
      size_t base = ((size_t)(bb_ * NHh + hh) * 1024 + gt) * 128;
      *(u32*)&outp[base + d2] = o1;
      *(u32*)&outp[base + 64 + d2] = o2;
    }
  } else {
    // V panel: compact (B*T, 1024) write for vtrans
    #pragma unroll
    for (int mf = 0; mf < 8; ++mf)
      #pragma unroll
      for (int j = 0; j < 4; ++j) {
        int r = bm + mf * 16 + gr * 4 + j;
        #pragma unroll
        for (int nf = 0; nf < 4; ++nf) {
          int vc = bn - 10240 + wn * 64 + nf * 16 + ln;
          vb[(size_t)r * 1024 + vc] = f2bf(acc[mf][nf][j]);
        }
      }
  }
}

// ====== 128x128 GEMM (out-projection), single barrier/K-tile (r12, verified) ======
#define STA(buf, t) { \
  gload16(Ab + (size_t)(t) * 64, (buf) + dsloc); \
  gload16(Ab + (size_t)32 * K + (size_t)(t) * 64, (buf) + 2048 + dsloc); \
  gload16(Ab + (size_t)64 * K + (size_t)(t) * 64, (buf) + 4096 + dsloc); \
  gload16(Ab + (size_t)96 * K + (size_t)(t) * 64, (buf) + 6144 + dsloc); }
#define STB(buf, t) { \
  gload16(Bb + (size_t)(t) * 64, (buf) + dsloc); \
  gload16(Bb + (size_t)32 * K + (size_t)(t) * 64, (buf) + 2048 + dsloc); \
  gload16(Bb + (size_t)64 * K + (size_t)(t) * 64, (buf) + 4096 + dsloc); \
  gload16(Bb + (size_t)96 * K + (size_t)(t) * 64, (buf) + 6144 + dsloc); }
#define MFMA16 { \
  acc[0][0] = __builtin_amdgcn_mfma_f32_16x16x32_bf16(a0, b0, acc[0][0], 0, 0, 0); \
  acc[0][1] = __builtin_amdgcn_mfma_f32_16x16x32_bf16(a0, b1, acc[0][1], 0, 0, 0); \
  acc[0][2] = __builtin_amdgcn_mfma_f32_16x16x32_bf16(a0, b2, acc[0][2], 0, 0, 0); \
  acc[0][3] = __builtin_amdgcn_mfma_f32_16x16x32_bf16(a0, b3, acc[0][3], 0, 0, 0); \
  acc[1][0] = __builtin_amdgcn_mfma_f32_16x16x32_bf16(a1, b0, acc[1][0], 0, 0, 0); \
  acc[1][1] = __builtin_amdgcn_mfma_f32_16x16x32_bf16(a1, b1, acc[1][1], 0, 0, 0); \
  acc[1][2] = __builtin_amdgcn_mfma_f32_16x16x32_bf16(a1, b2, acc[1][2], 0, 0, 0); \
  acc[1][3] = __builtin_amdgcn_mfma_f32_16x16x32_bf16(a1, b3, acc[1][3], 0, 0, 0); \
  acc[2][0] = __builtin_amdgcn_mfma_f32_16x16x32_bf16(a2, b0, acc[2][0], 0, 0, 0); \
  acc[2][1] = __builtin_amdgcn_mfma_f32_16x16x32_bf16(a2, b1, acc[2][1], 0, 0, 0); \
  acc[2][2] = __builtin_amdgcn_mfma_f32_16x16x32_bf16(a2, b2, acc[2][2], 0, 0, 0); \
  acc[2][3] = __builtin_amdgcn_mfma_f32_16x16x32_bf16(a2, b3, acc[2][3], 0, 0, 0); \
  acc[3][0] = __builtin_amdgcn_mfma_f32_16x16x32_bf16(a3, b0, acc[3][0], 0, 0, 0); \
  acc[3][1] = __builtin_amdgcn_mfma_f32_16x16x32_bf16(a3, b1, acc[3][1], 0, 0, 0); \
  acc[3][2] = __builtin_amdgcn_mfma_f32_16x16x32_bf16(a3, b2, acc[3][2], 0, 0, 0); \
  acc[3][3] = __builtin_amdgcn_mfma_f32_16x16x32_bf16(a3, b3, acc[3][3], 0, 0, 0); }

template <bool OUT_BF16>
__global__ __launch_bounds__(256, 2) void gemm8p(const u16* __restrict__ A,
                                                 const u16* __restrict__ Bt,
                                                 void* __restrict__ Cv,
                                                 int M, int N, int K, int TN) {
  extern __shared__ u16 lds[];
  const int tid = threadIdx.x;
  const int lane = tid & 63;
  const int wid = tid >> 6;
  const int wm = wid >> 1, wn = wid & 1;
  const int ln = lane & 15, gr = lane >> 4;
  const int NT = K >> 6;

  const int bid = blockIdx.x;
  const int bn = (bid % TN) * 128;
  const int bm = (bid / TN) * 128;

  const int srow = tid >> 3;
  const int sch = (tid & 7) ^ (srow & 7);
  const u16* Ab = A + (size_t)(bm + srow) * K + sch * 8;
  const u16* Bb = Bt + (size_t)(bn + srow) * K + sch * 8;
  const int dsloc = tid * 8;

  const int aro = (wm * 64 + ln) * 64;
  const int bro = (wn * 64 + ln) * 64;
  const int c0 = (gr ^ (ln & 7)) * 8;
  const int c1 = ((4 + gr) ^ (ln & 7)) * 8;

  f32x4 acc[4][4] = {};
  bf16x8 a0, a1, a2, a3, b0, b1, b2, b3;

  STA(lds, 0);
  STB(lds + 16384, 0);
  STB(lds + 24576, 1);
  asm volatile("s_waitcnt vmcnt(4)" ::: "memory");
  __builtin_amdgcn_s_barrier();

  int tm3 = 0;
  for (int t = 0; t < NT; ++t) {
    const u16* Ac = lds + (t & 1) * 8192;
    u16* An = lds + ((t + 1) & 1) * 8192;
    const u16* Bc = lds + 16384 + tm3 * 8192;
    int tn3 = tm3 + 2; if (tn3 >= 3) tn3 -= 3;
    u16* Bn = lds + 16384 + tn3 * 8192;

    a0 = *(const bf16x8*)&Ac[aro + c0];
    a1 = *(const bf16x8*)&Ac[aro + 1024 + c0];
    a2 = *(const bf16x8*)&Ac[aro + 2048 + c0];
    a3 = *(const bf16x8*)&Ac[aro + 3072 + c0];
    b0 = *(const bf16x8*)&Bc[bro + c0];
    b1 = *(const bf16x8*)&Bc[bro + 1024 + c0];
    b2 = *(const bf16x8*)&Bc[bro + 2048 + c0];
    b3 = *(const bf16x8*)&Bc[bro + 3072 + c0];
    if (t + 1 < NT) STA(An, t + 1);
    __builtin_amdgcn_s_setprio(1);
    MFMA16;
    __builtin_amdgcn_s_setprio(0);

    a0 = *(const bf16x8*)&Ac[aro + c1];
    a1 = *(const bf16x8*)&Ac[aro + 1024 + c1];
    a2 = *(const bf16x8*)&Ac[aro + 2048 + c1];
    a3 = *(const bf16x8*)&Ac[aro + 3072 + c1];
    b0 = *(const bf16x8*)&Bc[bro + c1];
    b1 = *(const bf16x8*)&Bc[bro + 1024 + c1];
    b2 = *(const bf16x8*)&Bc[bro + 2048 + c1];
    b3 = *(const bf16x8*)&Bc[bro + 3072 + c1];
    if (t + 2 < NT) {
      STB(Bn, t + 2);
      asm volatile("s_waitcnt vmcnt(4)" ::: "memory");
    } else {
      asm volatile("s_waitcnt vmcnt(0)" ::: "memory");
    }
    __builtin_amdgcn_s_setprio(1);
    MFMA16;
    __builtin_amdgcn_s_setprio(0);
    __builtin_amdgcn_s_barrier();

    tm3 = (tm3 + 1 == 3) ? 0 : tm3 + 1;
  }

  #pragma unroll
  for (int mf = 0; mf < 4; ++mf) {
    #pragma unroll
    for (int j = 0; j < 4; ++j) {
      int r = bm + wm * 64 + mf * 16 + gr * 4 + j;
      #pragma unroll
      for (int nf = 0; nf < 4; ++nf) {
        int c = bn + wn * 64 + nf * 16 + ln;
        if (OUT_BF16) ((u16*)Cv)[(size_t)r * N + c] = f2bf(acc[mf][nf][j]);
        else          ((float*)Cv)[(size_t)r * N + c] = acc[mf][nf][j];
      }
    }
  }
}

// ---- V transpose: vb (B*T, 1024) -> vt (B,Hk,128,T) bf16 ----
__global__ void vtrans_kernel(const u16* __restrict__ vb, u16* __restrict__ vt) {
  __shared__ u16 tile[32][34];
  int bh = blockIdx.z;               // b*8 + hk
  int t0 = blockIdx.x * 32, d0 = blockIdx.y * 32;
  int b = bh >> 3, hk = bh & 7;
  int x = threadIdx.x, y = threadIdx.y;   // (32,8)
  #pragma unroll
  for (int j = 0; j < 32; j += 8)
    tile[y + j][x] = vb[(size_t)(b * 1024 + t0 + y + j) * 1024 + hk * 128 + d0 + x];
  __syncthreads();
  #pragma unroll
  for (int j = 0; j < 32; j += 8)
    vt[((size_t)bh * 128 + d0 + y + j) * 1024 + t0 + x] = tile[x][y + j];
}

// ---------------- lambda per head ----------------
__global__ void lam_kernel(const float* __restrict__ lq1, const float* __restrict__ lk1,
                           const float* __restrict__ lq2, const float* __restrict__ lk2,
                           float* __restrict__ lam) {
  int h = blockIdx.x, l = threadIdx.x;   // 64 threads
  float p1 = lq1[h * 128 + l] * lk1[h * 128 + l] + lq1[h * 128 + 64 + l] * lk1[h * 128 + 64 + l];
  float p2 = lq2[h * 128 + l] * lk2[h * 128 + l] + lq2[h * 128 + 64 + l] * lk2[h * 128 + 64 + l];
  #pragma unroll
  for (int m = 32; m >= 1; m >>= 1) { p1 += __shfl_xor(p1, m); p2 += __shfl_xor(p2, m); }
  if (l == 0) lam[h] = expf(p1) - expf(p2) + LAMBDA_INIT_F;
}

// ======== fused dual flash attention + diff + RMS subln (r11, verified) ========
__global__ __launch_bounds__(512) void attn_kernel(const u16* __restrict__ qr,   // (B,64,T,128)
                                                   const u16* __restrict__ kr,   // (B,16,T,128)
                                                   const u16* __restrict__ vt,   // (B,8,128,T)
                                                   const float* __restrict__ lam,
                                                   const float* __restrict__ slw,
                                                   u16* __restrict__ attno) {    // (B*T, 4096)
  __shared__ u16 k1s[2][32 * 136];
  __shared__ u16 k2s[2][32 * 136];
  __shared__ u16 vs[2][128 * 40];
  __shared__ u16 ps[8][2][640];
  const int bx = blockIdx.x, h = blockIdx.y, b = blockIdx.z;
  const int qt = (b == 0) ? (7 - bx) : bx;   // complementary pairing
  const int tid = threadIdx.x, lane = tid & 63, w = tid >> 6;
  const int ln = lane & 15, gr = lane >> 4;
  const int hk = h >> 2;
  const int qrow0 = qt * 128 + w * 16;
  u16* psw1 = ps[w][0];
  u16* psw2 = ps[w][1];
  const float SL2E = 0.12751744006165926f;   // SCALE * log2(e)
  const float ML2E = 11.541560327111707f;    // 8 * log2(e)

  bf16x8 q1f[4], q2f[4];
  {
    const u16* q1p = qr + ((size_t)(b * 64 + h) * 1024 + qrow0 + ln) * 128 + gr * 8;
    const u16* q2p = qr + ((size_t)(b * 64 + 32 + h) * 1024 + qrow0 + ln) * 128 + gr * 8;
    #pragma unroll
    for (int ds = 0; ds < 4; ++ds) {
      q1f[ds] = *(const bf16x8*)(q1p + ds * 32);
      q2f[ds] = *(const bf16x8*)(q2p + ds * 32);
    }
  }
  f32x4 acc1[8] = {}, acc2[8] = {};
  float l1[4] = {0.f, 0.f, 0.f, 0.f}, l2[4] = {0.f, 0.f, 0.f, 0.f};

  const u16* k1g = kr + (size_t)(b * 16 + hk) * 1024 * 128;
  const u16* k2g = kr + (size_t)(b * 16 + 8 + hk) * 1024 * 128;
  const u16* vg = vt + (size_t)(b * 8 + hk) * 128 * 1024;
  const int nkt = 4 * qt + 4;

  const int krow = tid >> 4, kch = tid & 15;
  const int vdr = tid >> 2, vch = tid & 3;
  const u16* k1p = k1g + (size_t)krow * 128 + kch * 8;
  const u16* k2p = k2g + (size_t)krow * 128 + kch * 8;
  const u16* vp = vg + (size_t)vdr * 1024 + vch * 8;
  const int kdst = krow * 136 + kch * 8;
  const int vdst = vdr * 40 + vch * 8;

  bf16x8 r0 = *(const bf16x8*)(k1p);
  bf16x8 r1 = *(const bf16x8*)(k2p);
  bf16x8 r2 = *(const bf16x8*)(vp);
  *(bf16x8*)&k1s[0][kdst] = r0;
  *(bf16x8*)&k2s[0][kdst] = r1;
  *(bf16x8*)&vs[0][vdst] = r2;
  __syncthreads();

  int cur = 0;
  for (int kt = 0; kt < nkt; ++kt) {
    if (kt + 1 < nkt) {
      r0 = *(const bf16x8*)(k1p + (size_t)(kt + 1) * 4096);
      r1 = *(const bf16x8*)(k2p + (size_t)(kt + 1) * 4096);
      r2 = *(const bf16x8*)(vp + (size_t)(kt + 1) * 32);
    }

    f32x4 s1[2], s2[2];
    #pragma unroll
    for (int ct = 0; ct < 2; ++ct) {
      s1[ct] = (f32x4){0.f, 0.f, 0.f, 0.f};
      s2[ct] = (f32x4){0.f, 0.f, 0.f, 0.f};
      #pragma unroll
      for (int ds = 0; ds < 4; ++ds) {
        bf16x8 kf1 = *(const bf16x8*)&k1s[cur][(ct * 16 + ln) * 136 + ds * 32 + gr * 8];
        s1[ct] = __builtin_amdgcn_mfma_f32_16x16x32_bf16(q1f[ds], kf1, s1[ct], 0, 0, 0);
        bf16x8 kf2 = *(const bf16x8*)&k2s[cur][(ct * 16 + ln) * 136 + ds * 32 + gr * 8];
        s2[ct] = __builtin_amdgcn_mfma_f32_16x16x32_bf16(q2f[ds], kf2, s2[ct], 0, 0, 0);
      }
    }
    #pragma unroll
    for (int j = 0; j < 4; ++j) {
      int row = qrow0 + gr * 4 + j;
      bool msk0 = (kt * 32 + ln) > row;
      bool msk1 = (kt * 32 + 16 + ln) > row;
      float t10 = msk0 ? -1e30f : fmaf(s1[0][j], SL2E, -ML2E);
      float t11 = msk1 ? -1e30f : fmaf(s1[1][j], SL2E, -ML2E);
      float t20 = msk0 ? -1e30f : fmaf(s2[0][j], SL2E, -ML2E);
      float t21 = msk1 ? -1e30f : fmaf(s2[1][j], SL2E, -ML2E);
      u16 b10 = f2bf(exp2f(t10)), b11 = f2bf(exp2f(t11));
      u16 b20 = f2bf(exp2f(t20)), b21 = f2bf(exp2f(t21));
      int ro = (gr * 4 + j) * 40;
      psw1[ro + ln] = b10; psw1[ro + 16 + ln] = b11;
      psw2[ro + ln] = b20; psw2[ro + 16 + ln] = b21;
      l1[j] += bf2f(b10) + bf2f(b11);
      l2[j] += bf2f(b20) + bf2f(b21);
    }
    bf16x8 pf1 = *(const bf16x8*)&psw1[ln * 40 + gr * 8];
    bf16x8 pf2 = *(const bf16x8*)&psw2[ln * 40 + gr * 8];
    #pragma unroll
    for (int dt = 0; dt < 8; ++dt) {
      bf16x8 vf = *(const bf16x8*)&vs[cur][(dt * 16 + ln) * 40 + gr * 8];
      acc1[dt] = __builtin_amdgcn_mfma_f32_16x16x32_bf16(pf1, vf, acc1[dt], 0, 0, 0);
      acc2[dt] = __builtin_amdgcn_mfma_f32_16x16x32_bf16(pf2, vf, acc2[dt], 0, 0, 0);
    }

    if (kt + 1 < nkt) {
      *(bf16x8*)&k1s[cur ^ 1][kdst] = r0;
      *(bf16x8*)&k2s[cur ^ 1][kdst] = r1;
      *(bf16x8*)&vs[cur ^ 1][vdst] = r2;
    }
    __syncthreads();
    cur ^= 1;
  }

  float inv1[4], inv2[4];
  #pragma unroll
  for (int j = 0; j < 4; ++j) {
    float a = l1[j], c = l2[j];
    a += __shfl_xor(a, 1); a += __shfl_xor(a, 2); a += __shfl_xor(a, 4); a += __shfl_xor(a, 8);
    c += __shfl_xor(c, 1); c += __shfl_xor(c, 2); c += __shfl_xor(c, 4); c += __shfl_xor(c, 8);
    inv1[j] = 1.f / a;
    inv2[j] = 1.f / c;
  }

  float lamv = lam[h];
  float ssq[4] = {0.f, 0.f, 0.f, 0.f};
  #pragma unroll
  for (int dt = 0; dt < 8; ++dt)
    #pragma unroll
    for (int j = 0; j < 4; ++j) {
      float d = acc1[dt][j] * inv1[j] - lamv * (acc2[dt][j] * inv2[j]);
      acc1[dt][j] = d;
      ssq[j] += d * d;
    }
  #pragma unroll
  for (int j = 0; j < 4; ++j) {
    float s = ssq[j];
    s += __shfl_xor(s, 1);
    s += __shfl_xor(s, 2);
    s += __shfl_xor(s, 4);
    s += __shfl_xor(s, 8);
    ssq[j] = rsqrtf(s * (1.0f / 128.0f) + 1e-6f);
  }
  #pragma unroll
  for (int dt = 0; dt < 8; ++dt) {
    float wgt = slw[dt * 16 + ln];
    #pragma unroll
    for (int j = 0; j < 4; ++j) {
      int row = qrow0 + gr * 4 + j;
      attno[(size_t)(b * 1024 + row) * 4096 + h * 128 + dt * 16 + ln] = f2bf(acc1[dt][j] * ssq[j] * wgt);
    }
  }
}

extern "C" void kernel_launch(void* const* d_in, const int* in_sizes, int n_in,
                              void* d_out, int out_size, void* d_ws, size_t ws_size,
                              hipStream_t stream) {
  (void)in_sizes; (void)n_in; (void)out_size; (void)ws_size;
  const float* x    = (const float*)d_in[0];
  const float* cosp = (const float*)d_in[1];
  const float* sinp = (const float*)d_in[2];
  const float* wq   = (const float*)d_in[3];
  const float* wk   = (const float*)d_in[4];
  const float* wv   = (const float*)d_in[5];
  const float* wo   = (const float*)d_in[6];
  const float* lq1  = (const float*)d_in[7];
  const float* lk1  = (const float*)d_in[8];
  const float* lq2  = (const float*)d_in[9];
  const float* lk2  = (const float*)d_in[10];
  const float* slw  = (const float*)d_in[11];
  float* out = (float*)d_out;
  char* ws = (char*)d_ws;

  // workspace layout (lifetime overlays; peak 155.19 MB):
  u16* xb    = (u16*)(ws);
  u16* vtp   = (u16*)(ws);
  u16* wqkvt = (u16*)(ws + 16777216);
  u16* wot   = (u16*)(ws + 16777216);
  u16* attno = (u16*)(ws + 50331648);
  u16* qr    = (u16*)(ws + 109051904);
  u16* kr    = (u16*)(ws + 142606336);
  u16* vbuf  = (u16*)(ws + 150994944);
  float* lam = (float*)(ws + 155189248);

  // 1) casts + weight transposes (wq|wk|wv fused into one (11264,4096) B^T)
  cast_f32_bf16<<<8192, 256, 0, stream>>>((const float4*)x, (uint2*)xb, 2097152);
  trans_cast<<<dim3(256, 64), dim3(32, 8), 0, stream>>>(wq, wqkvt, 4096, 8192);
  trans_cast<<<dim3(64, 64),  dim3(32, 8), 0, stream>>>(wk, wqkvt + (size_t)8192 * 4096, 4096, 2048);
  trans_cast<<<dim3(32, 64),  dim3(32, 8), 0, stream>>>(wv, wqkvt + (size_t)10240 * 4096, 4096, 1024);
  // 2) fused QKV projection + RoPE + head-major layout (128x128, TN=88)
  gemmW<<<1408, 128, 49152, stream>>>(xb, wqkvt, vbuf, qr, kr, cosp, sinp, 4096, 88);
  // 3) V transpose (compact vbuf -> vt)
  vtrans_kernel<<<dim3(32, 4, 16), dim3(32, 8), 0, stream>>>(vbuf, vtp);
  // 4) wo transpose (into dead wqkvt region), lambda
  trans_cast<<<dim3(128, 64), dim3(32, 8), 0, stream>>>(wo, wot, 4096, 4096);
  lam_kernel<<<32, 64, 0, stream>>>(lq1, lk1, lq2, lk2, lam);
  // 5) dual causal flash attention + diff + RMS subln -> (2048,4096) bf16
  attn_kernel<<<dim3(8, 32, 2), 512, 0, stream>>>(qr, kr, vtp, lam, slw, attno);
  // 6) output projection -> f32
  gemm8p<false><<<512, 256, 81920, stream>>>(attno, wot, (void*)out, 2048, 4096, 4096, 32);
}

// Round 16
// 419.385 us; speedup vs baseline: 1.1228x; 1.1228x over previous
//
#include <hip/hip_runtime.h>
#include <hip/hip_bf16.h>
#include <stdint.h>

typedef unsigned short u16;
typedef unsigned int u32;
typedef short bf16x8 __attribute__((ext_vector_type(8)));
typedef float f32x4 __attribute__((ext_vector_type(4)));

#define SCALE_F 0.088388347648318447f   // 1/sqrt(128)
#define LAMBDA_INIT_F 0.2f
// B=2, T=1024, DIM=4096, H=32, Hk=8, D=128, NREP=4

__device__ __forceinline__ u16 f2bf(float f) {
  union { float f; u32 u; } v; v.f = f;
  u32 r = v.u + 0x7fffu + ((v.u >> 16) & 1u);   // RNE
  return (u16)(r >> 16);
}
__device__ __forceinline__ float bf2f(u16 u) {
  union { u32 u; float f; } v; v.u = ((u32)u) << 16;
  return v.f;
}

typedef __attribute__((address_space(1))) void gvoid_t;
typedef __attribute__((address_space(3))) void lvoid_t;
__device__ __forceinline__ void gload16(const void* g, void* l) {
  __builtin_amdgcn_global_load_lds((gvoid_t*)g, (lvoid_t*)l, 16, 0, 0);
}

// ---------------- elementwise cast f32 -> bf16 (vectorized) ----------------
__global__ void cast_f32_bf16(const float4* __restrict__ in, uint2* __restrict__ out, int n4) {
  int i = blockIdx.x * 256 + threadIdx.x;
  if (i >= n4) return;
  float4 v = in[i];
  uint2 o;
  o.x = (u32)f2bf(v.x) | ((u32)f2bf(v.y) << 16);
  o.y = (u32)f2bf(v.z) | ((u32)f2bf(v.w) << 16);
  out[i] = o;
}

// ------ transpose+cast: w (K,N) f32 -> wt (N,K) bf16, u32-packed stores ------
__global__ void trans_cast(const float* __restrict__ in, u16* __restrict__ out, int K, int N) {
  __shared__ float tile[64][33];
  int kt = blockIdx.y * 64, nt = blockIdx.x * 32;
  int x = threadIdx.x, y = threadIdx.y;   // (32,8)
  #pragma unroll
  for (int j = 0; j < 8; ++j)
    tile[y + j * 8][x] = in[(size_t)(kt + y + j * 8) * N + nt + x];
  __syncthreads();
  #pragma unroll
  for (int j = 0; j < 4; ++j) {
    int n = y * 4 + j;
    u32 pk = (u32)f2bf(tile[2 * x][n]) | ((u32)f2bf(tile[2 * x + 1][n]) << 16);
    *(u32*)&out[(size_t)(nt + n) * K + kt + 2 * x] = pk;
  }
}

// ====== gemmW (r13-verified): 128x256, BK=32, 4 waves, single barrier/K-tile ======
// RoPE + head-major transpose fused into the epilogue. Each 256-col panel is
// exactly 2 heads; acc staged to the dead main-loop LDS as bf16 (128 x 264),
// one barrier, u32-paired reads + float2 cos/sin -> coalesced u32 writes into
// qr/kr. V panels write compact (B,T,1024). Ring-3 / counted-vmcnt(6) /
// single end-of-tile barrier (r12 race audit).
#define SQA(buf, t) { \
  gload16(Aq + (size_t)(t) * 32, (buf) + qdst); \
  gload16(Aq + (size_t)64 * K + (size_t)(t) * 32, (buf) + 2048 + qdst); }
#define SQB(buf, t) { \
  gload16(Bq + (size_t)(t) * 32, (buf) + qdst); \
  gload16(Bq + (size_t)64 * K + (size_t)(t) * 32, (buf) + 2048 + qdst); \
  gload16(Bq + (size_t)128 * K + (size_t)(t) * 32, (buf) + 4096 + qdst); \
  gload16(Bq + (size_t)192 * K + (size_t)(t) * 32, (buf) + 6144 + qdst); }
#define QMFMA16(O) { \
  acc[O+0][0] = __builtin_amdgcn_mfma_f32_16x16x32_bf16(a0, b0, acc[O+0][0], 0, 0, 0); \
  acc[O+0][1] = __builtin_amdgcn_mfma_f32_16x16x32_bf16(a0, b1, acc[O+0][1], 0, 0, 0); \
  acc[O+0][2] = __builtin_amdgcn_mfma_f32_16x16x32_bf16(a0, b2, acc[O+0][2], 0, 0, 0); \
  acc[O+0][3] = __builtin_amdgcn_mfma_f32_16x16x32_bf16(a0, b3, acc[O+0][3], 0, 0, 0); \
  acc[O+1][0] = __builtin_amdgcn_mfma_f32_16x16x32_bf16(a1, b0, acc[O+1][0], 0, 0, 0); \
  acc[O+1][1] = __builtin_amdgcn_mfma_f32_16x16x32_bf16(a1, b1, acc[O+1][1], 0, 0, 0); \
  acc[O+1][2] = __builtin_amdgcn_mfma_f32_16x16x32_bf16(a1, b2, acc[O+1][2], 0, 0, 0); \
  acc[O+1][3] = __builtin_amdgcn_mfma_f32_16x16x32_bf16(a1, b3, acc[O+1][3], 0, 0, 0); \
  acc[O+2][0] = __builtin_amdgcn_mfma_f32_16x16x32_bf16(a2, b0, acc[O+2][0], 0, 0, 0); \
  acc[O+2][1] = __builtin_amdgcn_mfma_f32_16x16x32_bf16(a2, b1, acc[O+2][1], 0, 0, 0); \
  acc[O+2][2] = __builtin_amdgcn_mfma_f32_16x16x32_bf16(a2, b2, acc[O+2][2], 0, 0, 0); \
  acc[O+2][3] = __builtin_amdgcn_mfma_f32_16x16x32_bf16(a2, b3, acc[O+2][3], 0, 0, 0); \
  acc[O+3][0] = __builtin_amdgcn_mfma_f32_16x16x32_bf16(a3, b0, acc[O+3][0], 0, 0, 0); \
  acc[O+3][1] = __builtin_amdgcn_mfma_f32_16x16x32_bf16(a3, b1, acc[O+3][1], 0, 0, 0); \
  acc[O+3][2] = __builtin_amdgcn_mfma_f32_16x16x32_bf16(a3, b2, acc[O+3][2], 0, 0, 0); \
  acc[O+3][3] = __builtin_amdgcn_mfma_f32_16x16x32_bf16(a3, b3, acc[O+3][3], 0, 0, 0); }

__global__ __launch_bounds__(256, 2) void gemmW(const u16* __restrict__ A,
                                                const u16* __restrict__ Bt,
                                                u16* __restrict__ vb,   // (B*T, 1024) V out
                                                u16* __restrict__ qrp,  // (B,64,T,128)
                                                u16* __restrict__ krp,  // (B,16,T,128)
                                                const float* __restrict__ cosp,
                                                const float* __restrict__ sinp,
                                                int K, int TN) {
  extern __shared__ u16 lds[];   // A bufs: 0/4096/8192 (u16), B bufs: 12288/20480/28672
  const int tid = threadIdx.x;
  const int lane = tid & 63;
  const int wn = tid >> 6;
  const int ln = lane & 15, gr = lane >> 4;
  const int NT = K >> 5;

  const int bid = blockIdx.x;                // N-major
  const int bn = (bid % TN) * 256;
  const int bm = (bid / TN) * 128;

  const int sch = (tid & 3) ^ ((tid >> 3) & 3);
  const u16* Aq = A + (size_t)(bm + (tid >> 2)) * K + sch * 8;
  const u16* Bq = Bt + (size_t)(bn + (tid >> 2)) * K + sch * 8;
  const int qdst = tid * 8;

  const int cfo = (gr ^ ((ln >> 1) & 3)) * 8;
  const int ab = ln * 32 + cfo;
  const int bb = wn * 2048 + ln * 32 + cfo;

  f32x4 acc[8][4] = {};
  bf16x8 a0, a1, a2, a3, b0, b1, b2, b3;

  SQA(lds, 0);
  SQB(lds + 12288, 0);
  SQA(lds + 4096, 1);
  SQB(lds + 20480, 1);
  asm volatile("s_waitcnt vmcnt(6)" ::: "memory");
  __builtin_amdgcn_s_barrier();

  int tm3 = 0;
  for (int t = 0; t < NT; ++t) {
    const u16* Ac = lds + tm3 * 4096;
    const u16* Bc = lds + 12288 + tm3 * 8192;
    int tn3 = tm3 + 2; if (tn3 >= 3) tn3 -= 3;
    u16* An = lds + tn3 * 4096;
    u16* Bn = lds + 12288 + tn3 * 8192;

    a0 = *(const bf16x8*)&Ac[ab];
    a1 = *(const bf16x8*)&Ac[ab + 512];
    a2 = *(const bf16x8*)&Ac[ab + 1024];
    a3 = *(const bf16x8*)&Ac[ab + 1536];
    b0 = *(const bf16x8*)&Bc[bb];
    b1 = *(const bf16x8*)&Bc[bb + 512];
    b2 = *(const bf16x8*)&Bc[bb + 1024];
    b3 = *(const bf16x8*)&Bc[bb + 1536];
    if (t + 2 < NT) SQA(An, t + 2);
    __builtin_amdgcn_s_setprio(1);
    QMFMA16(0);
    __builtin_amdgcn_s_setprio(0);

    a0 = *(const bf16x8*)&Ac[ab + 2048];
    a1 = *(const bf16x8*)&Ac[ab + 2560];
    a2 = *(const bf16x8*)&Ac[ab + 3072];
    a3 = *(const bf16x8*)&Ac[ab + 3584];
    if (t + 2 < NT) {
      SQB(Bn, t + 2);
      asm volatile("s_waitcnt vmcnt(6)" ::: "memory");
    } else {
      asm volatile("s_waitcnt vmcnt(0)" ::: "memory");
    }
    __builtin_amdgcn_s_setprio(1);
    QMFMA16(4);
    __builtin_amdgcn_s_setprio(0);
    __builtin_amdgcn_s_barrier();          // single barrier per K-tile

    tm3 = (tm3 + 1 == 3) ? 0 : tm3 + 1;
  }

  // ---------------- fused epilogue ----------------
  if (bn < 10240) {
    // Q/K panel (2 heads): acc -> LDS bf16 (stride 264), barrier, rope, write
    #pragma unroll
    for (int mf = 0; mf < 8; ++mf)
      #pragma unroll
      for (int j = 0; j < 4; ++j) {
        int rl = mf * 16 + gr * 4 + j;
        #pragma unroll
        for (int nf = 0; nf < 4; ++nf)
          lds[rl * 264 + wn * 64 + nf * 16 + ln] = f2bf(acc[mf][nf][j]);
      }
    __syncthreads();
    const int bb_ = bm >> 10;              // batch (rows never cross b)
    const int gt0 = bm & 1023;             // sequence offset of row 0
    const bool isQ = (bn < 8192);
    const int hbase = isQ ? (bn >> 7) : ((bn - 8192) >> 7);
    const int NHh = isQ ? 64 : 16;
    u16* outp = isQ ? qrp : krp;
    const int tr = tid >> 5;               // 8 row-groups
    const int d2 = (tid & 31) * 2;         // even d, u32 granularity
    #pragma unroll
    for (int r8 = 0; r8 < 16; ++r8) {
      int t = r8 * 8 + tr;
      int gt = gt0 + t;
      float2 cc = *(const float2*)&cosp[gt * 64 + d2];
      float2 sv = *(const float2*)&sinp[gt * 64 + d2];
      #pragma unroll
      for (int hh = 0; hh < 2; ++hh) {
        u32 p1 = *(const u32*)&lds[t * 264 + hh * 128 + d2];
        u32 p2 = *(const u32*)&lds[t * 264 + hh * 128 + 64 + d2];
        float x1a = bf2f((u16)p1), x1b = bf2f((u16)(p1 >> 16));
        float x2a = bf2f((u16)p2), x2b = bf2f((u16)(p2 >> 16));
        u32 o1 = (u32)f2bf(x1a * cc.x - x2a * sv.x) | ((u32)f2bf(x1b * cc.y - x2b * sv.y) << 16);
        u32 o2 = (u32)f2bf(x2a * cc.x + x1a * sv.x) | ((u32)f2bf(x2b * cc.y + x1b * sv.y) << 16);
        size_t base = ((size_t)(bb_ * NHh + hbase + hh) * 1024 + gt) * 128;
        *(u32*)&outp[base + d2] = o1;
        *(u32*)&outp[base + 64 + d2] = o2;
      }
    }
  } else {
    // V panel: compact (B*T, 1024) write for vtrans
    #pragma unroll
    for (int mf = 0; mf < 8; ++mf)
      #pragma unroll
      for (int j = 0; j < 4; ++j) {
        int r = bm + mf * 16 + gr * 4 + j;
        #pragma unroll
        for (int nf = 0; nf < 4; ++nf) {
          int vc = bn - 10240 + wn * 64 + nf * 16 + ln;
          vb[(size_t)r * 1024 + vc] = f2bf(acc[mf][nf][j]);
        }
      }
  }
}

// ====== 128x128 GEMM (out-projection), single barrier/K-tile (r12, verified) ======
#define STA(buf, t) { \
  gload16(Ab + (size_t)(t) * 64, (buf) + dsloc); \
  gload16(Ab + (size_t)32 * K + (size_t)(t) * 64, (buf) + 2048 + dsloc); \
  gload16(Ab + (size_t)64 * K + (size_t)(t) * 64, (buf) + 4096 + dsloc); \
  gload16(Ab + (size_t)96 * K + (size_t)(t) * 64, (buf) + 6144 + dsloc); }
#define STB(buf, t) { \
  gload16(Bb + (size_t)(t) * 64, (buf) + dsloc); \
  gload16(Bb + (size_t)32 * K + (size_t)(t) * 64, (buf) + 2048 + dsloc); \
  gload16(Bb + (size_t)64 * K + (size_t)(t) * 64, (buf) + 4096 + dsloc); \
  gload16(Bb + (size_t)96 * K + (size_t)(t) * 64, (buf) + 6144 + dsloc); }
#define MFMA16 { \
  acc[0][0] = __builtin_amdgcn_mfma_f32_16x16x32_bf16(a0, b0, acc[0][0], 0, 0, 0); \
  acc[0][1] = __builtin_amdgcn_mfma_f32_16x16x32_bf16(a0, b1, acc[0][1], 0, 0, 0); \
  acc[0][2] = __builtin_amdgcn_mfma_f32_16x16x32_bf16(a0, b2, acc[0][2], 0, 0, 0); \
  acc[0][3] = __builtin_amdgcn_mfma_f32_16x16x32_bf16(a0, b3, acc[0][3], 0, 0, 0); \
  acc[1][0] = __builtin_amdgcn_mfma_f32_16x16x32_bf16(a1, b0, acc[1][0], 0, 0, 0); \
  acc[1][1] = __builtin_amdgcn_mfma_f32_16x16x32_bf16(a1, b1, acc[1][1], 0, 0, 0); \
  acc[1][2] = __builtin_amdgcn_mfma_f32_16x16x32_bf16(a1, b2, acc[1][2], 0, 0, 0); \
  acc[1][3] = __builtin_amdgcn_mfma_f32_16x16x32_bf16(a1, b3, acc[1][3], 0, 0, 0); \
  acc[2][0] = __builtin_amdgcn_mfma_f32_16x16x32_bf16(a2, b0, acc[2][0], 0, 0, 0); \
  acc[2][1] = __builtin_amdgcn_mfma_f32_16x16x32_bf16(a2, b1, acc[2][1], 0, 0, 0); \
  acc[2][2] = __builtin_amdgcn_mfma_f32_16x16x32_bf16(a2, b2, acc[2][2], 0, 0, 0); \
  acc[2][3] = __builtin_amdgcn_mfma_f32_16x16x32_bf16(a2, b3, acc[2][3], 0, 0, 0); \
  acc[3][0] = __builtin_amdgcn_mfma_f32_16x16x32_bf16(a3, b0, acc[3][0], 0, 0, 0); \
  acc[3][1] = __builtin_amdgcn_mfma_f32_16x16x32_bf16(a3, b1, acc[3][1], 0, 0, 0); \
  acc[3][2] = __builtin_amdgcn_mfma_f32_16x16x32_bf16(a3, b2, acc[3][2], 0, 0, 0); \
  acc[3][3] = __builtin_amdgcn_mfma_f32_16x16x32_bf16(a3, b3, acc[3][3], 0, 0, 0); }

template <bool OUT_BF16>
__global__ __launch_bounds__(256, 2) void gemm8p(const u16* __restrict__ A,
                                                 const u16* __restrict__ Bt,
                                                 void* __restrict__ Cv,
                                                 int M, int N, int K, int TN) {
  extern __shared__ u16 lds[];
  const int tid = threadIdx.x;
  const int lane = tid & 63;
  const int wid = tid >> 6;
  const int wm = wid >> 1, wn = wid & 1;
  const int ln = lane & 15, gr = lane >> 4;
  const int NT = K >> 6;

  const int bid = blockIdx.x;
  const int bn = (bid % TN) * 128;
  const int bm = (bid / TN) * 128;

  const int srow = tid >> 3;
  const int sch = (tid & 7) ^ (srow & 7);
  const u16* Ab = A + (size_t)(bm + srow) * K + sch * 8;
  const u16* Bb = Bt + (size_t)(bn + srow) * K + sch * 8;
  const int dsloc = tid * 8;

  const int aro = (wm * 64 + ln) * 64;
  const int bro = (wn * 64 + ln) * 64;
  const int c0 = (gr ^ (ln & 7)) * 8;
  const int c1 = ((4 + gr) ^ (ln & 7)) * 8;

  f32x4 acc[4][4] = {};
  bf16x8 a0, a1, a2, a3, b0, b1, b2, b3;

  STA(lds, 0);
  STB(lds + 16384, 0);
  STB(lds + 24576, 1);
  asm volatile("s_waitcnt vmcnt(4)" ::: "memory");
  __builtin_amdgcn_s_barrier();

  int tm3 = 0;
  for (int t = 0; t < NT; ++t) {
    const u16* Ac = lds + (t & 1) * 8192;
    u16* An = lds + ((t + 1) & 1) * 8192;
    const u16* Bc = lds + 16384 + tm3 * 8192;
    int tn3 = tm3 + 2; if (tn3 >= 3) tn3 -= 3;
    u16* Bn = lds + 16384 + tn3 * 8192;

    a0 = *(const bf16x8*)&Ac[aro + c0];
    a1 = *(const bf16x8*)&Ac[aro + 1024 + c0];
    a2 = *(const bf16x8*)&Ac[aro + 2048 + c0];
    a3 = *(const bf16x8*)&Ac[aro + 3072 + c0];
    b0 = *(const bf16x8*)&Bc[bro + c0];
    b1 = *(const bf16x8*)&Bc[bro + 1024 + c0];
    b2 = *(const bf16x8*)&Bc[bro + 2048 + c0];
    b3 = *(const bf16x8*)&Bc[bro + 3072 + c0];
    if (t + 1 < NT) STA(An, t + 1);
    __builtin_amdgcn_s_setprio(1);
    MFMA16;
    __builtin_amdgcn_s_setprio(0);

    a0 = *(const bf16x8*)&Ac[aro + c1];
    a1 = *(const bf16x8*)&Ac[aro + 1024 + c1];
    a2 = *(const bf16x8*)&Ac[aro + 2048 + c1];
    a3 = *(const bf16x8*)&Ac[aro + 3072 + c1];
    b0 = *(const bf16x8*)&Bc[bro + c1];
    b1 = *(const bf16x8*)&Bc[bro + 1024 + c1];
    b2 = *(const bf16x8*)&Bc[bro + 2048 + c1];
    b3 = *(const bf16x8*)&Bc[bro + 3072 + c1];
    if (t + 2 < NT) {
      STB(Bn, t + 2);
      asm volatile("s_waitcnt vmcnt(4)" ::: "memory");
    } else {
      asm volatile("s_waitcnt vmcnt(0)" ::: "memory");
    }
    __builtin_amdgcn_s_setprio(1);
    MFMA16;
    __builtin_amdgcn_s_setprio(0);
    __builtin_amdgcn_s_barrier();

    tm3 = (tm3 + 1 == 3) ? 0 : tm3 + 1;
  }

  #pragma unroll
  for (int mf = 0; mf < 4; ++mf) {
    #pragma unroll
    for (int j = 0; j < 4; ++j) {
      int r = bm + wm * 64 + mf * 16 + gr * 4 + j;
      #pragma unroll
      for (int nf = 0; nf < 4; ++nf) {
        int c = bn + wn * 64 + nf * 16 + ln;
        if (OUT_BF16) ((u16*)Cv)[(size_t)r * N + c] = f2bf(acc[mf][nf][j]);
        else          ((float*)Cv)[(size_t)r * N + c] = acc[mf][nf][j];
      }
    }
  }
}

// ---- V transpose: vb (B*T, 1024) -> vt (B,Hk,128,T) bf16 ----
__global__ void vtrans_kernel(const u16* __restrict__ vb, u16* __restrict__ vt) {
  __shared__ u16 tile[32][34];
  int bh = blockIdx.z;               // b*8 + hk
  int t0 = blockIdx.x * 32, d0 = blockIdx.y * 32;
  int b = bh >> 3, hk = bh & 7;
  int x = threadIdx.x, y = threadIdx.y;   // (32,8)
  #pragma unroll
  for (int j = 0; j < 32; j += 8)
    tile[y + j][x] = vb[(size_t)(b * 1024 + t0 + y + j) * 1024 + hk * 128 + d0 + x];
  __syncthreads();
  #pragma unroll
  for (int j = 0; j < 32; j += 8)
    vt[((size_t)bh * 128 + d0 + y + j) * 1024 + t0 + x] = tile[x][y + j];
}

// ---------------- lambda per head ----------------
__global__ void lam_kernel(const float* __restrict__ lq1, const float* __restrict__ lk1,
                           const float* __restrict__ lq2, const float* __restrict__ lk2,
                           float* __restrict__ lam) {
  int h = blockIdx.x, l = threadIdx.x;   // 64 threads
  float p1 = lq1[h * 128 + l] * lk1[h * 128 + l] + lq1[h * 128 + 64 + l] * lk1[h * 128 + 64 + l];
  float p2 = lq2[h * 128 + l] * lk2[h * 128 + l] + lq2[h * 128 + 64 + l] * lk2[h * 128 + 64 + l];
  #pragma unroll
  for (int m = 32; m >= 1; m >>= 1) { p1 += __shfl_xor(p1, m); p2 += __shfl_xor(p2, m); }
  if (l == 0) lam[h] = expf(p1) - expf(p2) + LAMBDA_INIT_F;
}

// ======== fused dual flash attention + diff + RMS subln (r11, verified) ========
__global__ __launch_bounds__(512) void attn_kernel(const u16* __restrict__ qr,   // (B,64,T,128)
                                                   const u16* __restrict__ kr,   // (B,16,T,128)
                                                   const u16* __restrict__ vt,   // (B,8,128,T)
                                                   const float* __restrict__ lam,
                                                   const float* __restrict__ slw,
                                                   u16* __restrict__ attno) {    // (B*T, 4096)
  __shared__ u16 k1s[2][32 * 136];
  __shared__ u16 k2s[2][32 * 136];
  __shared__ u16 vs[2][128 * 40];
  __shared__ u16 ps[8][2][640];
  const int bx = blockIdx.x, h = blockIdx.y, b = blockIdx.z;
  const int qt = (b == 0) ? (7 - bx) : bx;   // complementary pairing
  const int tid = threadIdx.x, lane = tid & 63, w = tid >> 6;
  const int ln = lane & 15, gr = lane >> 4;
  const int hk = h >> 2;
  const int qrow0 = qt * 128 + w * 16;
  u16* psw1 = ps[w][0];
  u16* psw2 = ps[w][1];
  const float SL2E = 0.12751744006165926f;   // SCALE * log2(e)
  const float ML2E = 11.541560327111707f;    // 8 * log2(e)

  bf16x8 q1f[4], q2f[4];
  {
    const u16* q1p = qr + ((size_t)(b * 64 + h) * 1024 + qrow0 + ln) * 128 + gr * 8;
    const u16* q2p = qr + ((size_t)(b * 64 + 32 + h) * 1024 + qrow0 + ln) * 128 + gr * 8;
    #pragma unroll
    for (int ds = 0; ds < 4; ++ds) {
      q1f[ds] = *(const bf16x8*)(q1p + ds * 32);
      q2f[ds] = *(const bf16x8*)(q2p + ds * 32);
    }
  }
  f32x4 acc1[8] = {}, acc2[8] = {};
  float l1[4] = {0.f, 0.f, 0.f, 0.f}, l2[4] = {0.f, 0.f, 0.f, 0.f};

  const u16* k1g = kr + (size_t)(b * 16 + hk) * 1024 * 128;
  const u16* k2g = kr + (size_t)(b * 16 + 8 + hk) * 1024 * 128;
  const u16* vg = vt + (size_t)(b * 8 + hk) * 128 * 1024;
  const int nkt = 4 * qt + 4;

  const int krow = tid >> 4, kch = tid & 15;
  const int vdr = tid >> 2, vch = tid & 3;
  const u16* k1p = k1g + (size_t)krow * 128 + kch * 8;
  const u16* k2p = k2g + (size_t)krow * 128 + kch * 8;
  const u16* vp = vg + (size_t)vdr * 1024 + vch * 8;
  const int kdst = krow * 136 + kch * 8;
  const int vdst = vdr * 40 + vch * 8;

  bf16x8 r0 = *(const bf16x8*)(k1p);
  bf16x8 r1 = *(const bf16x8*)(k2p);
  bf16x8 r2 = *(const bf16x8*)(vp);
  *(bf16x8*)&k1s[0][kdst] = r0;
  *(bf16x8*)&k2s[0][kdst] = r1;
  *(bf16x8*)&vs[0][vdst] = r2;
  __syncthreads();

  int cur = 0;
  for (int kt = 0; kt < nkt; ++kt) {
    if (kt + 1 < nkt) {
      r0 = *(const bf16x8*)(k1p + (size_t)(kt + 1) * 4096);
      r1 = *(const bf16x8*)(k2p + (size_t)(kt + 1) * 4096);
      r2 = *(const bf16x8*)(vp + (size_t)(kt + 1) * 32);
    }

    f32x4 s1[2], s2[2];
    #pragma unroll
    for (int ct = 0; ct < 2; ++ct) {
      s1[ct] = (f32x4){0.f, 0.f, 0.f, 0.f};
      s2[ct] = (f32x4){0.f, 0.f, 0.f, 0.f};
      #pragma unroll
      for (int ds = 0; ds < 4; ++ds) {
        bf16x8 kf1 = *(const bf16x8*)&k1s[cur][(ct * 16 + ln) * 136 + ds * 32 + gr * 8];
        s1[ct] = __builtin_amdgcn_mfma_f32_16x16x32_bf16(q1f[ds], kf1, s1[ct], 0, 0, 0);
        bf16x8 kf2 = *(const bf16x8*)&k2s[cur][(ct * 16 + ln) * 136 + ds * 32 + gr * 8];
        s2[ct] = __builtin_amdgcn_mfma_f32_16x16x32_bf16(q2f[ds], kf2, s2[ct], 0, 0, 0);
      }
    }
    #pragma unroll
    for (int j = 0; j < 4; ++j) {
      int row = qrow0 + gr * 4 + j;
      bool msk0 = (kt * 32 + ln) > row;
      bool msk1 = (kt * 32 + 16 + ln) > row;
      float t10 = msk0 ? -1e30f : fmaf(s1[0][j], SL2E, -ML2E);
      float t11 = msk1 ? -1e30f : fmaf(s1[1][j], SL2E, -ML2E);
      float t20 = msk0 ? -1e30f : fmaf(s2[0][j], SL2E, -ML2E);
      float t21 = msk1 ? -1e30f : fmaf(s2[1][j], SL2E, -ML2E);
      u16 b10 = f2bf(exp2f(t10)), b11 = f2bf(exp2f(t11));
      u16 b20 = f2bf(exp2f(t20)), b21 = f2bf(exp2f(t21));
      int ro = (gr * 4 + j) * 40;
      psw1[ro + ln] = b10; psw1[ro + 16 + ln] = b11;
      psw2[ro + ln] = b20; psw2[ro + 16 + ln] = b21;
      l1[j] += bf2f(b10) + bf2f(b11);
      l2[j] += bf2f(b20) + bf2f(b21);
    }
    bf16x8 pf1 = *(const bf16x8*)&psw1[ln * 40 + gr * 8];
    bf16x8 pf2 = *(const bf16x8*)&psw2[ln * 40 + gr * 8];
    #pragma unroll
    for (int dt = 0; dt < 8; ++dt) {
      bf16x8 vf = *(const bf16x8*)&vs[cur][(dt * 16 + ln) * 40 + gr * 8];
      acc1[dt] = __builtin_amdgcn_mfma_f32_16x16x32_bf16(pf1, vf, acc1[dt], 0, 0, 0);
      acc2[dt] = __builtin_amdgcn_mfma_f32_16x16x32_bf16(pf2, vf, acc2[dt], 0, 0, 0);
    }

    if (kt + 1 < nkt) {
      *(bf16x8*)&k1s[cur ^ 1][kdst] = r0;
      *(bf16x8*)&k2s[cur ^ 1][kdst] = r1;
      *(bf16x8*)&vs[cur ^ 1][vdst] = r2;
    }
    __syncthreads();
    cur ^= 1;
  }

  float inv1[4], inv2[4];
  #pragma unroll
  for (int j = 0; j < 4; ++j) {
    float a = l1[j], c = l2[j];
    a += __shfl_xor(a, 1); a += __shfl_xor(a, 2); a += __shfl_xor(a, 4); a += __shfl_xor(a, 8);
    c += __shfl_xor(c, 1); c += __shfl_xor(c, 2); c += __shfl_xor(c, 4); c += __shfl_xor(c, 8);
    inv1[j] = 1.f / a;
    inv2[j] = 1.f / c;
  }

  float lamv = lam[h];
  float ssq[4] = {0.f, 0.f, 0.f, 0.f};
  #pragma unroll
  for (int dt = 0; dt < 8; ++dt)
    #pragma unroll
    for (int j = 0; j < 4; ++j) {
      float d = acc1[dt][j] * inv1[j] - lamv * (acc2[dt][j] * inv2[j]);
      acc1[dt][j] = d;
      ssq[j] += d * d;
    }
  #pragma unroll
  for (int j = 0; j < 4; ++j) {
    float s = ssq[j];
    s += __shfl_xor(s, 1);
    s += __shfl_xor(s, 2);
    s += __shfl_xor(s, 4);
    s += __shfl_xor(s, 8);
    ssq[j] = rsqrtf(s * (1.0f / 128.0f) + 1e-6f);
  }
  #pragma unroll
  for (int dt = 0; dt < 8; ++dt) {
    float wgt = slw[dt * 16 + ln];
    #pragma unroll
    for (int j = 0; j < 4; ++j) {
      int row = qrow0 + gr * 4 + j;
      attno[(size_t)(b * 1024 + row) * 4096 + h * 128 + dt * 16 + ln] = f2bf(acc1[dt][j] * ssq[j] * wgt);
    }
  }
}

extern "C" void kernel_launch(void* const* d_in, const int* in_sizes, int n_in,
                              void* d_out, int out_size, void* d_ws, size_t ws_size,
                              hipStream_t stream) {
  (void)in_sizes; (void)n_in; (void)out_size; (void)ws_size;
  const float* x    = (const float*)d_in[0];
  const float* cosp = (const float*)d_in[1];
  const float* sinp = (const float*)d_in[2];
  const float* wq   = (const float*)d_in[3];
  const float* wk   = (const float*)d_in[4];
  const float* wv   = (const float*)d_in[5];
  const float* wo   = (const float*)d_in[6];
  const float* lq1  = (const float*)d_in[7];
  const float* lk1  = (const float*)d_in[8];
  const float* lq2  = (const float*)d_in[9];
  const float* lk2  = (const float*)d_in[10];
  const float* slw  = (const float*)d_in[11];
  float* out = (float*)d_out;
  char* ws = (char*)d_ws;

  // workspace layout (lifetime overlays; peak 155.19 MB):
  // [0,16.78M):       xb (cast->gemmW), then vtp (vtrans->attn)
  // [16.78M,109.05M): wqkvt (trans->gemmW), then wot(33.55M)+attno(16.78M)
  // [109.05M,142.6M): qr (gemmW->attn)
  // [142.6M,151.0M):  kr (gemmW->attn)
  // [151.0M,155.2M):  vbuf (gemmW->vtrans)
  u16* xb    = (u16*)(ws);
  u16* vtp   = (u16*)(ws);
  u16* wqkvt = (u16*)(ws + 16777216);
  u16* wot   = (u16*)(ws + 16777216);
  u16* attno = (u16*)(ws + 50331648);
  u16* qr    = (u16*)(ws + 109051904);
  u16* kr    = (u16*)(ws + 142606336);
  u16* vbuf  = (u16*)(ws + 150994944);
  float* lam = (float*)(ws + 155189248);

  // 1) casts + weight transposes (wq|wk|wv fused into one (11264,4096) B^T)
  cast_f32_bf16<<<8192, 256, 0, stream>>>((const float4*)x, (uint2*)xb, 2097152);
  trans_cast<<<dim3(256, 64), dim3(32, 8), 0, stream>>>(wq, wqkvt, 4096, 8192);
  trans_cast<<<dim3(64, 64),  dim3(32, 8), 0, stream>>>(wk, wqkvt + (size_t)8192 * 4096, 4096, 2048);
  trans_cast<<<dim3(32, 64),  dim3(32, 8), 0, stream>>>(wv, wqkvt + (size_t)10240 * 4096, 4096, 1024);
  // 2) fused QKV projection + RoPE + head-major layout (rope kernels deleted)
  gemmW<<<704, 256, 73728, stream>>>(xb, wqkvt, vbuf, qr, kr, cosp, sinp, 4096, 44);
  // 3) V transpose (compact vbuf -> vt)
  vtrans_kernel<<<dim3(32, 4, 16), dim3(32, 8), 0, stream>>>(vbuf, vtp);
  // 4) wo transpose (into dead wqkvt region), lambda
  trans_cast<<<dim3(128, 64), dim3(32, 8), 0, stream>>>(wo, wot, 4096, 4096);
  lam_kernel<<<32, 64, 0, stream>>>(lq1, lk1, lq2, lk2, lam);
  // 5) dual causal flash attention + diff + RMS subln -> (2048,4096) bf16
  attn_kernel<<<dim3(8, 32, 2), 512, 0, stream>>>(qr, kr, vtp, lam, slw, attno);
  // 6) output projection -> f32
  gemm8p<false><<<512, 256, 81920, stream>>>(attno, wot, (void*)out, 2048, 4096, 4096, 32);
}

// Round 17
// 417.943 us; speedup vs baseline: 1.1266x; 1.0034x over previous
//
#include <hip/hip_runtime.h>
#include <hip/hip_bf16.h>
#include <stdint.h>

typedef unsigned short u16;
typedef unsigned int u32;
typedef short bf16x8 __attribute__((ext_vector_type(8)));
typedef float f32x4 __attribute__((ext_vector_type(4)));

#define SCALE_F 0.088388347648318447f   // 1/sqrt(128)
#define LAMBDA_INIT_F 0.2f
// B=2, T=1024, DIM=4096, H=32, Hk=8, D=128, NREP=4

__device__ __forceinline__ u16 f2bf(float f) {
  union { float f; u32 u; } v; v.f = f;
  u32 r = v.u + 0x7fffu + ((v.u >> 16) & 1u);   // RNE
  return (u16)(r >> 16);
}
__device__ __forceinline__ float bf2f(u16 u) {
  union { u32 u; float f; } v; v.u = ((u32)u) << 16;
  return v.f;
}

typedef __attribute__((address_space(1))) void gvoid_t;
typedef __attribute__((address_space(3))) void lvoid_t;
__device__ __forceinline__ void gload16(const void* g, void* l) {
  __builtin_amdgcn_global_load_lds((gvoid_t*)g, (lvoid_t*)l, 16, 0, 0);
}

// ---------------- elementwise cast f32 -> bf16 (vectorized) ----------------
__global__ void cast_f32_bf16(const float4* __restrict__ in, uint2* __restrict__ out, int n4) {
  int i = blockIdx.x * 256 + threadIdx.x;
  if (i >= n4) return;
  float4 v = in[i];
  uint2 o;
  o.x = (u32)f2bf(v.x) | ((u32)f2bf(v.y) << 16);
  o.y = (u32)f2bf(v.z) | ((u32)f2bf(v.w) << 16);
  out[i] = o;
}

// ------ transpose+cast: w (K,N) f32 -> wt (N,K) bf16, u32-packed stores ------
__global__ void trans_cast(const float* __restrict__ in, u16* __restrict__ out, int K, int N) {
  __shared__ float tile[64][33];
  int kt = blockIdx.y * 64, nt = blockIdx.x * 32;
  int x = threadIdx.x, y = threadIdx.y;   // (32,8)
  #pragma unroll
  for (int j = 0; j < 8; ++j)
    tile[y + j * 8][x] = in[(size_t)(kt + y + j * 8) * N + nt + x];
  __syncthreads();
  #pragma unroll
  for (int j = 0; j < 4; ++j) {
    int n = y * 4 + j;
    u32 pk = (u32)f2bf(tile[2 * x][n]) | ((u32)f2bf(tile[2 * x + 1][n]) << 16);
    *(u32*)&out[(size_t)(nt + n) * K + kt + 2 * x] = pk;
  }
}

// ====== gemmW (r17): 128x256, BK=32, 4 waves, single barrier/K-tile ======
// r17 change: M-MAJOR raster (bm = bid % TM, bn = bid / TM). Capacity rule
// learned from r14/r15: the operand spread across the whole kernel must fit
// cache (A, 17 MB -> L2/L3 resident), and the operand that can't fit (B,
// 92 MB) gets its 16 consumer blocks CONSECUTIVE -> co-resident -> each
// 2 MB panel fetched ~once. Old N-major did the opposite (B refetched
// ~4.5x = 440 MB). Everything else identical to r13-verified kernel.
#define SQA(buf, t) { \
  gload16(Aq + (size_t)(t) * 32, (buf) + qdst); \
  gload16(Aq + (size_t)64 * K + (size_t)(t) * 32, (buf) + 2048 + qdst); }
#define SQB(buf, t) { \
  gload16(Bq + (size_t)(t) * 32, (buf) + qdst); \
  gload16(Bq + (size_t)64 * K + (size_t)(t) * 32, (buf) + 2048 + qdst); \
  gload16(Bq + (size_t)128 * K + (size_t)(t) * 32, (buf) + 4096 + qdst); \
  gload16(Bq + (size_t)192 * K + (size_t)(t) * 32, (buf) + 6144 + qdst); }
#define QMFMA16(O) { \
  acc[O+0][0] = __builtin_amdgcn_mfma_f32_16x16x32_bf16(a0, b0, acc[O+0][0], 0, 0, 0); \
  acc[O+0][1] = __builtin_amdgcn_mfma_f32_16x16x32_bf16(a0, b1, acc[O+0][1], 0, 0, 0); \
  acc[O+0][2] = __builtin_amdgcn_mfma_f32_16x16x32_bf16(a0, b2, acc[O+0][2], 0, 0, 0); \
  acc[O+0][3] = __builtin_amdgcn_mfma_f32_16x16x32_bf16(a0, b3, acc[O+0][3], 0, 0, 0); \
  acc[O+1][0] = __builtin_amdgcn_mfma_f32_16x16x32_bf16(a1, b0, acc[O+1][0], 0, 0, 0); \
  acc[O+1][1] = __builtin_amdgcn_mfma_f32_16x16x32_bf16(a1, b1, acc[O+1][1], 0, 0, 0); \
  acc[O+1][2] = __builtin_amdgcn_mfma_f32_16x16x32_bf16(a1, b2, acc[O+1][2], 0, 0, 0); \
  acc[O+1][3] = __builtin_amdgcn_mfma_f32_16x16x32_bf16(a1, b3, acc[O+1][3], 0, 0, 0); \
  acc[O+2][0] = __builtin_amdgcn_mfma_f32_16x16x32_bf16(a2, b0, acc[O+2][0], 0, 0, 0); \
  acc[O+2][1] = __builtin_amdgcn_mfma_f32_16x16x32_bf16(a2, b1, acc[O+2][1], 0, 0, 0); \
  acc[O+2][2] = __builtin_amdgcn_mfma_f32_16x16x32_bf16(a2, b2, acc[O+2][2], 0, 0, 0); \
  acc[O+2][3] = __builtin_amdgcn_mfma_f32_16x16x32_bf16(a2, b3, acc[O+2][3], 0, 0, 0); \
  acc[O+3][0] = __builtin_amdgcn_mfma_f32_16x16x32_bf16(a3, b0, acc[O+3][0], 0, 0, 0); \
  acc[O+3][1] = __builtin_amdgcn_mfma_f32_16x16x32_bf16(a3, b1, acc[O+3][1], 0, 0, 0); \
  acc[O+3][2] = __builtin_amdgcn_mfma_f32_16x16x32_bf16(a3, b2, acc[O+3][2], 0, 0, 0); \
  acc[O+3][3] = __builtin_amdgcn_mfma_f32_16x16x32_bf16(a3, b3, acc[O+3][3], 0, 0, 0); }

__global__ __launch_bounds__(256, 2) void gemmW(const u16* __restrict__ A,
                                                const u16* __restrict__ Bt,
                                                u16* __restrict__ vb,   // (B*T, 1024) V out
                                                u16* __restrict__ qrp,  // (B,64,T,128)
                                                u16* __restrict__ krp,  // (B,16,T,128)
                                                const float* __restrict__ cosp,
                                                const float* __restrict__ sinp,
                                                int K, int TM) {
  extern __shared__ u16 lds[];   // A bufs: 0/4096/8192 (u16), B bufs: 12288/20480/28672
  const int tid = threadIdx.x;
  const int lane = tid & 63;
  const int wn = tid >> 6;
  const int ln = lane & 15, gr = lane >> 4;
  const int NT = K >> 5;

  const int bid = blockIdx.x;                // M-MAJOR raster (r17)
  const int bm = (bid % TM) * 128;
  const int bn = (bid / TM) * 256;

  const int sch = (tid & 3) ^ ((tid >> 3) & 3);
  const u16* Aq = A + (size_t)(bm + (tid >> 2)) * K + sch * 8;
  const u16* Bq = Bt + (size_t)(bn + (tid >> 2)) * K + sch * 8;
  const int qdst = tid * 8;

  const int cfo = (gr ^ ((ln >> 1) & 3)) * 8;
  const int ab = ln * 32 + cfo;
  const int bb = wn * 2048 + ln * 32 + cfo;

  f32x4 acc[8][4] = {};
  bf16x8 a0, a1, a2, a3, b0, b1, b2, b3;

  SQA(lds, 0);
  SQB(lds + 12288, 0);
  SQA(lds + 4096, 1);
  SQB(lds + 20480, 1);
  asm volatile("s_waitcnt vmcnt(6)" ::: "memory");
  __builtin_amdgcn_s_barrier();

  int tm3 = 0;
  for (int t = 0; t < NT; ++t) {
    const u16* Ac = lds + tm3 * 4096;
    const u16* Bc = lds + 12288 + tm3 * 8192;
    int tn3 = tm3 + 2; if (tn3 >= 3) tn3 -= 3;
    u16* An = lds + tn3 * 4096;
    u16* Bn = lds + 12288 + tn3 * 8192;

    a0 = *(const bf16x8*)&Ac[ab];
    a1 = *(const bf16x8*)&Ac[ab + 512];
    a2 = *(const bf16x8*)&Ac[ab + 1024];
    a3 = *(const bf16x8*)&Ac[ab + 1536];
    b0 = *(const bf16x8*)&Bc[bb];
    b1 = *(const bf16x8*)&Bc[bb + 512];
    b2 = *(const bf16x8*)&Bc[bb + 1024];
    b3 = *(const bf16x8*)&Bc[bb + 1536];
    if (t + 2 < NT) SQA(An, t + 2);
    __builtin_amdgcn_s_setprio(1);
    QMFMA16(0);
    __builtin_amdgcn_s_setprio(0);

    a0 = *(const bf16x8*)&Ac[ab + 2048];
    a1 = *(const bf16x8*)&Ac[ab + 2560];
    a2 = *(const bf16x8*)&Ac[ab + 3072];
    a3 = *(const bf16x8*)&Ac[ab + 3584];
    if (t + 2 < NT) {
      SQB(Bn, t + 2);
      asm volatile("s_waitcnt vmcnt(6)" ::: "memory");
    } else {
      asm volatile("s_waitcnt vmcnt(0)" ::: "memory");
    }
    __builtin_amdgcn_s_setprio(1);
    QMFMA16(4);
    __builtin_amdgcn_s_setprio(0);
    __builtin_amdgcn_s_barrier();          // single barrier per K-tile

    tm3 = (tm3 + 1 == 3) ? 0 : tm3 + 1;
  }

  // ---------------- fused epilogue ----------------
  if (bn < 10240) {
    // Q/K panel (2 heads): acc -> LDS bf16 (stride 264), barrier, rope, write
    #pragma unroll
    for (int mf = 0; mf < 8; ++mf)
      #pragma unroll
      for (int j = 0; j < 4; ++j) {
        int rl = mf * 16 + gr * 4 + j;
        #pragma unroll
        for (int nf = 0; nf < 4; ++nf)
          lds[rl * 264 + wn * 64 + nf * 16 + ln] = f2bf(acc[mf][nf][j]);
      }
    __syncthreads();
    const int bb_ = bm >> 10;              // batch (rows never cross b)
    const int gt0 = bm & 1023;             // sequence offset of row 0
    const bool isQ = (bn < 8192);
    const int hbase = isQ ? (bn >> 7) : ((bn - 8192) >> 7);
    const int NHh = isQ ? 64 : 16;
    u16* outp = isQ ? qrp : krp;
    const int tr = tid >> 5;               // 8 row-groups
    const int d2 = (tid & 31) * 2;         // even d, u32 granularity
    #pragma unroll
    for (int r8 = 0; r8 < 16; ++r8) {
      int t = r8 * 8 + tr;
      int gt = gt0 + t;
      float2 cc = *(const float2*)&cosp[gt * 64 + d2];
      float2 sv = *(const float2*)&sinp[gt * 64 + d2];
      #pragma unroll
      for (int hh = 0; hh < 2; ++hh) {
        u32 p1 = *(const u32*)&lds[t * 264 + hh * 128 + d2];
        u32 p2 = *(const u32*)&lds[t * 264 + hh * 128 + 64 + d2];
        float x1a = bf2f((u16)p1), x1b = bf2f((u16)(p1 >> 16));
        float x2a = bf2f((u16)p2), x2b = bf2f((u16)(p2 >> 16));
        u32 o1 = (u32)f2bf(x1a * cc.x - x2a * sv.x) | ((u32)f2bf(x1b * cc.y - x2b * sv.y) << 16);
        u32 o2 = (u32)f2bf(x2a * cc.x + x1a * sv.x) | ((u32)f2bf(x2b * cc.y + x1b * sv.y) << 16);
        size_t base = ((size_t)(bb_ * NHh + hbase + hh) * 1024 + gt) * 128;
        *(u32*)&outp[base + d2] = o1;
        *(u32*)&outp[base + 64 + d2] = o2;
      }
    }
  } else {
    // V panel: compact (B*T, 1024) write for vtrans
    #pragma unroll
    for (int mf = 0; mf < 8; ++mf)
      #pragma unroll
      for (int j = 0; j < 4; ++j) {
        int r = bm + mf * 16 + gr * 4 + j;
        #pragma unroll
        for (int nf = 0; nf < 4; ++nf) {
          int vc = bn - 10240 + wn * 64 + nf * 16 + ln;
          vb[(size_t)r * 1024 + vc] = f2bf(acc[mf][nf][j]);
        }
      }
  }
}

// ====== 128x128 GEMM (out-projection), single barrier/K-tile (r12, verified) ======
#define STA(buf, t) { \
  gload16(Ab + (size_t)(t) * 64, (buf) + dsloc); \
  gload16(Ab + (size_t)32 * K + (size_t)(t) * 64, (buf) + 2048 + dsloc); \
  gload16(Ab + (size_t)64 * K + (size_t)(t) * 64, (buf) + 4096 + dsloc); \
  gload16(Ab + (size_t)96 * K + (size_t)(t) * 64, (buf) + 6144 + dsloc); }
#define STB(buf, t) { \
  gload16(Bb + (size_t)(t) * 64, (buf) + dsloc); \
  gload16(Bb + (size_t)32 * K + (size_t)(t) * 64, (buf) + 2048 + dsloc); \
  gload16(Bb + (size_t)64 * K + (size_t)(t) * 64, (buf) + 4096 + dsloc); \
  gload16(Bb + (size_t)96 * K + (size_t)(t) * 64, (buf) + 6144 + dsloc); }
#define MFMA16 { \
  acc[0][0] = __builtin_amdgcn_mfma_f32_16x16x32_bf16(a0, b0, acc[0][0], 0, 0, 0); \
  acc[0][1] = __builtin_amdgcn_mfma_f32_16x16x32_bf16(a0, b1, acc[0][1], 0, 0, 0); \
  acc[0][2] = __builtin_amdgcn_mfma_f32_16x16x32_bf16(a0, b2, acc[0][2], 0, 0, 0); \
  acc[0][3] = __builtin_amdgcn_mfma_f32_16x16x32_bf16(a0, b3, acc[0][3], 0, 0, 0); \
  acc[1][0] = __builtin_amdgcn_mfma_f32_16x16x32_bf16(a1, b0, acc[1][0], 0, 0, 0); \
  acc[1][1] = __builtin_amdgcn_mfma_f32_16x16x32_bf16(a1, b1, acc[1][1], 0, 0, 0); \
  acc[1][2] = __builtin_amdgcn_mfma_f32_16x16x32_bf16(a1, b2, acc[1][2], 0, 0, 0); \
  acc[1][3] = __builtin_amdgcn_mfma_f32_16x16x32_bf16(a1, b3, acc[1][3], 0, 0, 0); \
  acc[2][0] = __builtin_amdgcn_mfma_f32_16x16x32_bf16(a2, b0, acc[2][0], 0, 0, 0); \
  acc[2][1] = __builtin_amdgcn_mfma_f32_16x16x32_bf16(a2, b1, acc[2][1], 0, 0, 0); \
  acc[2][2] = __builtin_amdgcn_mfma_f32_16x16x32_bf16(a2, b2, acc[2][2], 0, 0, 0); \
  acc[2][3] = __builtin_amdgcn_mfma_f32_16x16x32_bf16(a2, b3, acc[2][3], 0, 0, 0); \
  acc[3][0] = __builtin_amdgcn_mfma_f32_16x16x32_bf16(a3, b0, acc[3][0], 0, 0, 0); \
  acc[3][1] = __builtin_amdgcn_mfma_f32_16x16x32_bf16(a3, b1, acc[3][1], 0, 0, 0); \
  acc[3][2] = __builtin_amdgcn_mfma_f32_16x16x32_bf16(a3, b2, acc[3][2], 0, 0, 0); \
  acc[3][3] = __builtin_amdgcn_mfma_f32_16x16x32_bf16(a3, b3, acc[3][3], 0, 0, 0); }

template <bool OUT_BF16>
__global__ __launch_bounds__(256, 2) void gemm8p(const u16* __restrict__ A,
                                                 const u16* __restrict__ Bt,
                                                 void* __restrict__ Cv,
                                                 int M, int N, int K, int TN) {
  extern __shared__ u16 lds[];
  const int tid = threadIdx.x;
  const int lane = tid & 63;
  const int wid = tid >> 6;
  const int wm = wid >> 1, wn = wid & 1;
  const int ln = lane & 15, gr = lane >> 4;
  const int NT = K >> 6;

  const int bid = blockIdx.x;
  const int bn = (bid % TN) * 128;
  const int bm = (bid / TN) * 128;

  const int srow = tid >> 3;
  const int sch = (tid & 7) ^ (srow & 7);
  const u16* Ab = A + (size_t)(bm + srow) * K + sch * 8;
  const u16* Bb = Bt + (size_t)(bn + srow) * K + sch * 8;
  const int dsloc = tid * 8;

  const int aro = (wm * 64 + ln) * 64;
  const int bro = (wn * 64 + ln) * 64;
  const int c0 = (gr ^ (ln & 7)) * 8;
  const int c1 = ((4 + gr) ^ (ln & 7)) * 8;

  f32x4 acc[4][4] = {};
  bf16x8 a0, a1, a2, a3, b0, b1, b2, b3;

  STA(lds, 0);
  STB(lds + 16384, 0);
  STB(lds + 24576, 1);
  asm volatile("s_waitcnt vmcnt(4)" ::: "memory");
  __builtin_amdgcn_s_barrier();

  int tm3 = 0;
  for (int t = 0; t < NT; ++t) {
    const u16* Ac = lds + (t & 1) * 8192;
    u16* An = lds + ((t + 1) & 1) * 8192;
    const u16* Bc = lds + 16384 + tm3 * 8192;
    int tn3 = tm3 + 2; if (tn3 >= 3) tn3 -= 3;
    u16* Bn = lds + 16384 + tn3 * 8192;

    a0 = *(const bf16x8*)&Ac[aro + c0];
    a1 = *(const bf16x8*)&Ac[aro + 1024 + c0];
    a2 = *(const bf16x8*)&Ac[aro + 2048 + c0];
    a3 = *(const bf16x8*)&Ac[aro + 3072 + c0];
    b0 = *(const bf16x8*)&Bc[bro + c0];
    b1 = *(const bf16x8*)&Bc[bro + 1024 + c0];
    b2 = *(const bf16x8*)&Bc[bro + 2048 + c0];
    b3 = *(const bf16x8*)&Bc[bro + 3072 + c0];
    if (t + 1 < NT) STA(An, t + 1);
    __builtin_amdgcn_s_setprio(1);
    MFMA16;
    __builtin_amdgcn_s_setprio(0);

    a0 = *(const bf16x8*)&Ac[aro + c1];
    a1 = *(const bf16x8*)&Ac[aro + 1024 + c1];
    a2 = *(const bf16x8*)&Ac[aro + 2048 + c1];
    a3 = *(const bf16x8*)&Ac[aro + 3072 + c1];
    b0 = *(const bf16x8*)&Bc[bro + c1];
    b1 = *(const bf16x8*)&Bc[bro + 1024 + c1];
    b2 = *(const bf16x8*)&Bc[bro + 2048 + c1];
    b3 = *(const bf16x8*)&Bc[bro + 3072 + c1];
    if (t + 2 < NT) {
      STB(Bn, t + 2);
      asm volatile("s_waitcnt vmcnt(4)" ::: "memory");
    } else {
      asm volatile("s_waitcnt vmcnt(0)" ::: "memory");
    }
    __builtin_amdgcn_s_setprio(1);
    MFMA16;
    __builtin_amdgcn_s_setprio(0);
    __builtin_amdgcn_s_barrier();

    tm3 = (tm3 + 1 == 3) ? 0 : tm3 + 1;
  }

  #pragma unroll
  for (int mf = 0; mf < 4; ++mf) {
    #pragma unroll
    for (int j = 0; j < 4; ++j) {
      int r = bm + wm * 64 + mf * 16 + gr * 4 + j;
      #pragma unroll
      for (int nf = 0; nf < 4; ++nf) {
        int c = bn + wn * 64 + nf * 16 + ln;
        if (OUT_BF16) ((u16*)Cv)[(size_t)r * N + c] = f2bf(acc[mf][nf][j]);
        else          ((float*)Cv)[(size_t)r * N + c] = acc[mf][nf][j];
      }
    }
  }
}

// ---- V transpose: vb (B*T, 1024) -> vt (B,Hk,128,T) bf16 ----
__global__ void vtrans_kernel(const u16* __restrict__ vb, u16* __restrict__ vt) {
  __shared__ u16 tile[32][34];
  int bh = blockIdx.z;               // b*8 + hk
  int t0 = blockIdx.x * 32, d0 = blockIdx.y * 32;
  int b = bh >> 3, hk = bh & 7;
  int x = threadIdx.x, y = threadIdx.y;   // (32,8)
  #pragma unroll
  for (int j = 0; j < 32; j += 8)
    tile[y + j][x] = vb[(size_t)(b * 1024 + t0 + y + j) * 1024 + hk * 128 + d0 + x];
  __syncthreads();
  #pragma unroll
  for (int j = 0; j < 32; j += 8)
    vt[((size_t)bh * 128 + d0 + y + j) * 1024 + t0 + x] = tile[x][y + j];
}

// ---------------- lambda per head ----------------
__global__ void lam_kernel(const float* __restrict__ lq1, const float* __restrict__ lk1,
                           const float* __restrict__ lq2, const float* __restrict__ lk2,
                           float* __restrict__ lam) {
  int h = blockIdx.x, l = threadIdx.x;   // 64 threads
  float p1 = lq1[h * 128 + l] * lk1[h * 128 + l] + lq1[h * 128 + 64 + l] * lk1[h * 128 + 64 + l];
  float p2 = lq2[h * 128 + l] * lk2[h * 128 + l] + lq2[h * 128 + 64 + l] * lk2[h * 128 + 64 + l];
  #pragma unroll
  for (int m = 32; m >= 1; m >>= 1) { p1 += __shfl_xor(p1, m); p2 += __shfl_xor(p2, m); }
  if (l == 0) lam[h] = expf(p1) - expf(p2) + LAMBDA_INIT_F;
}

// ======== fused dual flash attention + diff + RMS subln (r11, verified) ========
__global__ __launch_bounds__(512) void attn_kernel(const u16* __restrict__ qr,   // (B,64,T,128)
                                                   const u16* __restrict__ kr,   // (B,16,T,128)
                                                   const u16* __restrict__ vt,   // (B,8,128,T)
                                                   const float* __restrict__ lam,
                                                   const float* __restrict__ slw,
                                                   u16* __restrict__ attno) {    // (B*T, 4096)
  __shared__ u16 k1s[2][32 * 136];
  __shared__ u16 k2s[2][32 * 136];
  __shared__ u16 vs[2][128 * 40];
  __shared__ u16 ps[8][2][640];
  const int bx = blockIdx.x, h = blockIdx.y, b = blockIdx.z;
  const int qt = (b == 0) ? (7 - bx) : bx;   // complementary pairing
  const int tid = threadIdx.x, lane = tid & 63, w = tid >> 6;
  const int ln = lane & 15, gr = lane >> 4;
  const int hk = h >> 2;
  const int qrow0 = qt * 128 + w * 16;
  u16* psw1 = ps[w][0];
  u16* psw2 = ps[w][1];
  const float SL2E = 0.12751744006165926f;   // SCALE * log2(e)
  const float ML2E = 11.541560327111707f;    // 8 * log2(e)

  bf16x8 q1f[4], q2f[4];
  {
    const u16* q1p = qr + ((size_t)(b * 64 + h) * 1024 + qrow0 + ln) * 128 + gr * 8;
    const u16* q2p = qr + ((size_t)(b * 64 + 32 + h) * 1024 + qrow0 + ln) * 128 + gr * 8;
    #pragma unroll
    for (int ds = 0; ds < 4; ++ds) {
      q1f[ds] = *(const bf16x8*)(q1p + ds * 32);
      q2f[ds] = *(const bf16x8*)(q2p + ds * 32);
    }
  }
  f32x4 acc1[8] = {}, acc2[8] = {};
  float l1[4] = {0.f, 0.f, 0.f, 0.f}, l2[4] = {0.f, 0.f, 0.f, 0.f};

  const u16* k1g = kr + (size_t)(b * 16 + hk) * 1024 * 128;
  const u16* k2g = kr + (size_t)(b * 16 + 8 + hk) * 1024 * 128;
  const u16* vg = vt + (size_t)(b * 8 + hk) * 128 * 1024;
  const int nkt = 4 * qt + 4;

  const int krow = tid >> 4, kch = tid & 15;
  const int vdr = tid >> 2, vch = tid & 3;
  const u16* k1p = k1g + (size_t)krow * 128 + kch * 8;
  const u16* k2p = k2g + (size_t)krow * 128 + kch * 8;
  const u16* vp = vg + (size_t)vdr * 1024 + vch * 8;
  const int kdst = krow * 136 + kch * 8;
  const int vdst = vdr * 40 + vch * 8;

  bf16x8 r0 = *(const bf16x8*)(k1p);
  bf16x8 r1 = *(const bf16x8*)(k2p);
  bf16x8 r2 = *(const bf16x8*)(vp);
  *(bf16x8*)&k1s[0][kdst] = r0;
  *(bf16x8*)&k2s[0][kdst] = r1;
  *(bf16x8*)&vs[0][vdst] = r2;
  __syncthreads();

  int cur = 0;
  for (int kt = 0; kt < nkt; ++kt) {
    if (kt + 1 < nkt) {
      r0 = *(const bf16x8*)(k1p + (size_t)(kt + 1) * 4096);
      r1 = *(const bf16x8*)(k2p + (size_t)(kt + 1) * 4096);
      r2 = *(const bf16x8*)(vp + (size_t)(kt + 1) * 32);
    }

    f32x4 s1[2], s2[2];
    #pragma unroll
    for (int ct = 0; ct < 2; ++ct) {
      s1[ct] = (f32x4){0.f, 0.f, 0.f, 0.f};
      s2[ct] = (f32x4){0.f, 0.f, 0.f, 0.f};
      #pragma unroll
      for (int ds = 0; ds < 4; ++ds) {
        bf16x8 kf1 = *(const bf16x8*)&k1s[cur][(ct * 16 + ln) * 136 + ds * 32 + gr * 8];
        s1[ct] = __builtin_amdgcn_mfma_f32_16x16x32_bf16(q1f[ds], kf1, s1[ct], 0, 0, 0);
        bf16x8 kf2 = *(const bf16x8*)&k2s[cur][(ct * 16 + ln) * 136 + ds * 32 + gr * 8];
        s2[ct] = __builtin_amdgcn_mfma_f32_16x16x32_bf16(q2f[ds], kf2, s2[ct], 0, 0, 0);
      }
    }
    #pragma unroll
    for (int j = 0; j < 4; ++j) {
      int row = qrow0 + gr * 4 + j;
      bool msk0 = (kt * 32 + ln) > row;
      bool msk1 = (kt * 32 + 16 + ln) > row;
      float t10 = msk0 ? -1e30f : fmaf(s1[0][j], SL2E, -ML2E);
      float t11 = msk1 ? -1e30f : fmaf(s1[1][j], SL2E, -ML2E);
      float t20 = msk0 ? -1e30f : fmaf(s2[0][j], SL2E, -ML2E);
      float t21 = msk1 ? -1e30f : fmaf(s2[1][j], SL2E, -ML2E);
      u16 b10 = f2bf(exp2f(t10)), b11 = f2bf(exp2f(t11));
      u16 b20 = f2bf(exp2f(t20)), b21 = f2bf(exp2f(t21));
      int ro = (gr * 4 + j) * 40;
      psw1[ro + ln] = b10; psw1[ro + 16 + ln] = b11;
      psw2[ro + ln] = b20; psw2[ro + 16 + ln] = b21;
      l1[j] += bf2f(b10) + bf2f(b11);
      l2[j] += bf2f(b20) + bf2f(b21);
    }
    bf16x8 pf1 = *(const bf16x8*)&psw1[ln * 40 + gr * 8];
    bf16x8 pf2 = *(const bf16x8*)&psw2[ln * 40 + gr * 8];
    #pragma unroll
    for (int dt = 0; dt < 8; ++dt) {
      bf16x8 vf = *(const bf16x8*)&vs[cur][(dt * 16 + ln) * 40 + gr * 8];
      acc1[dt] = __builtin_amdgcn_mfma_f32_16x16x32_bf16(pf1, vf, acc1[dt], 0, 0, 0);
      acc2[dt] = __builtin_amdgcn_mfma_f32_16x16x32_bf16(pf2, vf, acc2[dt], 0, 0, 0);
    }

    if (kt + 1 < nkt) {
      *(bf16x8*)&k1s[cur ^ 1][kdst] = r0;
      *(bf16x8*)&k2s[cur ^ 1][kdst] = r1;
      *(bf16x8*)&vs[cur ^ 1][vdst] = r2;
    }
    __syncthreads();
    cur ^= 1;
  }

  float inv1[4], inv2[4];
  #pragma unroll
  for (int j = 0; j < 4; ++j) {
    float a = l1[j], c = l2[j];
    a += __shfl_xor(a, 1); a += __shfl_xor(a, 2); a += __shfl_xor(a, 4); a += __shfl_xor(a, 8);
    c += __shfl_xor(c, 1); c += __shfl_xor(c, 2); c += __shfl_xor(c, 4); c += __shfl_xor(c, 8);
    inv1[j] = 1.f / a;
    inv2[j] = 1.f / c;
  }

  float lamv = lam[h];
  float ssq[4] = {0.f, 0.f, 0.f, 0.f};
  #pragma unroll
  for (int dt = 0; dt < 8; ++dt)
    #pragma unroll
    for (int j = 0; j < 4; ++j) {
      float d = acc1[dt][j] * inv1[j] - lamv * (acc2[dt][j] * inv2[j]);
      acc1[dt][j] = d;
      ssq[j] += d * d;
    }
  #pragma unroll
  for (int j = 0; j < 4; ++j) {
    float s = ssq[j];
    s += __shfl_xor(s, 1);
    s += __shfl_xor(s, 2);
    s += __shfl_xor(s, 4);
    s += __shfl_xor(s, 8);
    ssq[j] = rsqrtf(s * (1.0f / 128.0f) + 1e-6f);
  }
  #pragma unroll
  for (int dt = 0; dt < 8; ++dt) {
    float wgt = slw[dt * 16 + ln];
    #pragma unroll
    for (int j = 0; j < 4; ++j) {
      int row = qrow0 + gr * 4 + j;
      attno[(size_t)(b * 1024 + row) * 4096 + h * 128 + dt * 16 + ln] = f2bf(acc1[dt][j] * ssq[j] * wgt);
    }
  }
}

extern "C" void kernel_launch(void* const* d_in, const int* in_sizes, int n_in,
                              void* d_out, int out_size, void* d_ws, size_t ws_size,
                              hipStream_t stream) {
  (void)in_sizes; (void)n_in; (void)out_size; (void)ws_size;
  const float* x    = (const float*)d_in[0];
  const float* cosp = (const float*)d_in[1];
  const float* sinp = (const float*)d_in[2];
  const float* wq   = (const float*)d_in[3];
  const float* wk   = (const float*)d_in[4];
  const float* wv   = (const float*)d_in[5];
  const float* wo   = (const float*)d_in[6];
  const float* lq1  = (const float*)d_in[7];
  const float* lk1  = (const float*)d_in[8];
  const float* lq2  = (const float*)d_in[9];
  const float* lk2  = (const float*)d_in[10];
  const float* slw  = (const float*)d_in[11];
  float* out = (float*)d_out;
  char* ws = (char*)d_ws;

  // workspace layout (lifetime overlays; peak 155.19 MB):
  u16* xb    = (u16*)(ws);
  u16* vtp   = (u16*)(ws);
  u16* wqkvt = (u16*)(ws + 16777216);
  u16* wot   = (u16*)(ws + 16777216);
  u16* attno = (u16*)(ws + 50331648);
  u16* qr    = (u16*)(ws + 109051904);
  u16* kr    = (u16*)(ws + 142606336);
  u16* vbuf  = (u16*)(ws + 150994944);
  float* lam = (float*)(ws + 155189248);

  // 1) casts + weight transposes (wq|wk|wv fused into one (11264,4096) B^T)
  cast_f32_bf16<<<8192, 256, 0, stream>>>((const float4*)x, (uint2*)xb, 2097152);
  trans_cast<<<dim3(256, 64), dim3(32, 8), 0, stream>>>(wq, wqkvt, 4096, 8192);
  trans_cast<<<dim3(64, 64),  dim3(32, 8), 0, stream>>>(wk, wqkvt + (size_t)8192 * 4096, 4096, 2048);
  trans_cast<<<dim3(32, 64),  dim3(32, 8), 0, stream>>>(wv, wqkvt + (size_t)10240 * 4096, 4096, 1024);
  // 2) fused QKV projection + RoPE + head-major layout (M-major raster, TM=16)
  gemmW<<<704, 256, 73728, stream>>>(xb, wqkvt, vbuf, qr, kr, cosp, sinp, 4096, 16);
  // 3) V transpose (compact vbuf -> vt)
  vtrans_kernel<<<dim3(32, 4, 16), dim3(32, 8), 0, stream>>>(vbuf, vtp);
  // 4) wo transpose (into dead wqkvt region), lambda
  trans_cast<<<dim3(128, 64), dim3(32, 8), 0, stream>>>(wo, wot, 4096, 4096);
  lam_kernel<<<32, 64, 0, stream>>>(lq1, lk1, lq2, lk2, lam);
  // 5) dual causal flash attention + diff + RMS subln -> (2048,4096) bf16
  attn_kernel<<<dim3(8, 32, 2), 512, 0, stream>>>(qr, kr, vtp, lam, slw, attno);
  // 6) output projection -> f32
  gemm8p<false><<<512, 256, 81920, stream>>>(attno, wot, (void*)out, 2048, 4096, 4096, 32);
}